// Round 8
// baseline (223.372 us; speedup 1.0000x reference)
//
#include <hip/hip_runtime.h>
#include <stdint.h>

#define Nn 50000
#define Ee 800000
#define FIN 128
#define HIDD 256
#define CLSS 64

#define NBIN 98          // ceil(50000 / 512)
#define BSH 9
#define BINSZ 512
#define BCAP 16384
#define EPB 2048
#define NEB ((Ee + EPB - 1) / EPB)   // 391

typedef unsigned int uint_t;
typedef unsigned short us_t;
typedef __attribute__((ext_vector_type(8))) short short8;
typedef __attribute__((ext_vector_type(4))) float f32x4;
typedef __attribute__((ext_vector_type(2))) float f32x2;

__device__ inline float bflo(uint_t v) { union { uint_t u; float f; } c; c.u = v << 16; return c.f; }
__device__ inline float bfhi(uint_t v) { union { uint_t u; float f; } c; c.u = v & 0xffff0000u; return c.f; }
__device__ inline us_t f2bf(float f) {
    union { float f; uint_t u; } c; c.f = f;
    uint_t u = c.u;
    u += 0x7fffu + ((u >> 16) & 1u);
    return (us_t)(u >> 16);
}

#define GLOAD(gp, lp)                                                      \
    __builtin_amdgcn_global_load_lds(                                      \
        (const __attribute__((address_space(1))) unsigned int*)(gp),       \
        (__attribute__((address_space(3))) unsigned int*)(lp), 16, 0, 0)

// ---------------- x convert: bf16 (for GEMM) + fp8 (for gather), one pass ----------------
__global__ void k_cvtx(const float* __restrict__ xu, const float* __restrict__ xp,
                       us_t* __restrict__ ou, us_t* __restrict__ op,
                       uint_t* __restrict__ f8u, uint_t* __restrict__ f8p, int n4) {
    const float* in = blockIdx.y ? xp : xu;
    us_t* out = blockIdx.y ? op : ou;
    uint_t* o8 = blockIdx.y ? f8p : f8u;
    int i = blockIdx.x * 256 + threadIdx.x;
    int stride = gridDim.x * 256;
    for (; i < n4; i += stride) {
        float4 v = reinterpret_cast<const float4*>(in)[i];
        ushort4 o;
        o.x = f2bf(v.x); o.y = f2bf(v.y); o.z = f2bf(v.z); o.w = f2bf(v.w);
        reinterpret_cast<ushort4*>(out)[i] = o;
        int pk = __builtin_amdgcn_cvt_pk_fp8_f32(v.x, v.y, 0, false);
        pk = __builtin_amdgcn_cvt_pk_fp8_f32(v.z, v.w, pk, true);
        o8[i] = (uint_t)pk;
    }
}

// ---------------- weight convert + bin_cnt zero (one launch) ----------------
__global__ void k_cvtw(const float* __restrict__ w1, const float* __restrict__ w2,
                       const float* __restrict__ w3, const float* __restrict__ w4,
                       const float* __restrict__ w5, const float* __restrict__ w6,
                       const float* __restrict__ w7, const float* __restrict__ w8,
                       us_t* __restrict__ o1, us_t* __restrict__ o2,
                       us_t* __restrict__ o3, us_t* __restrict__ o4,
                       us_t* __restrict__ o5, us_t* __restrict__ o6,
                       us_t* __restrict__ o7, us_t* __restrict__ o8,
                       int* __restrict__ bin_cnt) {
    if (blockIdx.x == 192) {
        int t = threadIdx.x;
        if (t < 2 * NBIN) bin_cnt[t] = 0;
        return;
    }
    int i = blockIdx.x * 256 + threadIdx.x;
    const float* wp; us_t* op; int loc;
    if (i < 32768) {
        int seg = i >> 13; loc = i & 8191;
        switch (seg) {
            case 0: wp = w1; op = o1; break;
            case 1: wp = w2; op = o2; break;
            case 2: wp = w3; op = o3; break;
            default: wp = w4; op = o4; break;
        }
    } else {
        int j = i - 32768;
        int seg = j >> 12; loc = j & 4095;
        switch (seg) {
            case 0: wp = w5; op = o5; break;
            case 1: wp = w6; op = o6; break;
            case 2: wp = w7; op = o7; break;
            default: wp = w8; op = o8; break;
        }
    }
    float4 v = reinterpret_cast<const float4*>(wp)[loc];
    ushort4 o;
    o.x = f2bf(v.x); o.y = f2bf(v.y); o.z = f2bf(v.z); o.w = f2bf(v.w);
    reinterpret_cast<ushort4*>(op)[loc] = o;
}

// ---------------- binned CSR build ----------------
__global__ __launch_bounds__(256) void k_bin(const int* __restrict__ ei,
                                             int* __restrict__ bin_cnt,
                                             uint_t* __restrict__ ent_p,
                                             uint_t* __restrict__ ent_u) {
    __shared__ int hist[2 * NBIN];
    __shared__ int base[2 * NBIN];
    int tid = threadIdx.x;
    int e0 = blockIdx.x * EPB;
    int n = Ee - e0; if (n > EPB) n = EPB;

    for (int i = tid; i < 2 * NBIN; i += 256) hist[i] = 0;
    __syncthreads();
    for (int i = tid; i < n; i += 256) {
        int u = ei[e0 + i], p = ei[Ee + e0 + i];
        atomicAdd(&hist[p >> BSH], 1);
        atomicAdd(&hist[NBIN + (u >> BSH)], 1);
    }
    __syncthreads();
    for (int i = tid; i < 2 * NBIN; i += 256) {
        int c = hist[i];
        base[i] = c ? atomicAdd(&bin_cnt[i], c) : 0;
    }
    __syncthreads();
    for (int i = tid; i < 2 * NBIN; i += 256) hist[i] = base[i];
    __syncthreads();
    for (int i = tid; i < n; i += 256) {
        int u = ei[e0 + i], p = ei[Ee + e0 + i];
        int bp = p >> BSH, bu = u >> BSH;
        int rp = atomicAdd(&hist[bp], 1);
        if (rp < BCAP)
            ent_p[(size_t)bp * BCAP + rp] = ((uint_t)(p & (BINSZ - 1)) << 16) | (uint_t)u;
        int ru = atomicAdd(&hist[NBIN + bu], 1);
        if (ru < BCAP)
            ent_u[(size_t)bu * BCAP + ru] = ((uint_t)(u & (BINSZ - 1)) << 16) | (uint_t)p;
    }
}

__global__ void k_binscan(const int* __restrict__ bin_cnt, int* __restrict__ bin_base) {
    __shared__ int buf[2][128];
    int t = threadIdx.x;
    int side = t >> 7, i = t & 127;
    int v = 0;
    if (i < NBIN) { v = bin_cnt[side * NBIN + i]; if (v > BCAP) v = BCAP; }
    buf[side][i] = v;
    __syncthreads();
    #pragma unroll
    for (int d = 1; d < 128; d <<= 1) {
        int x = (i >= d) ? buf[side][i - d] : 0;
        __syncthreads();
        buf[side][i] += x;
        __syncthreads();
    }
    if (i < NBIN) bin_base[side * NBIN + i] = buf[side][i] - v;
}

__global__ __launch_bounds__(512) void k_scatter(
    const uint_t* __restrict__ ent_p, const uint_t* __restrict__ ent_u,
    const int* __restrict__ bin_cnt, const int* __restrict__ bin_base,
    int* __restrict__ off, int* __restrict__ cnt,
    int* __restrict__ src_p, int* __restrict__ src_u) {
    __shared__ int ca[BINSZ];
    __shared__ int cb[BINSZ];
    int side = blockIdx.y, b = blockIdx.x, t = threadIdx.x;
    const uint_t* E = (side ? ent_u : ent_p) + (size_t)b * BCAP;
    int* src = side ? src_u : src_p;
    int nb = bin_cnt[side * NBIN + b]; if (nb > BCAP) nb = BCAP;
    int base = bin_base[side * NBIN + b];

    ca[t] = 0;
    __syncthreads();
    for (int i = t; i < nb; i += 512)
        atomicAdd(&ca[E[i] >> 16], 1);
    __syncthreads();
    int v = ca[t];
    int* A = ca; int* B = cb;
    #pragma unroll
    for (int d = 1; d < BINSZ; d <<= 1) {
        int x = A[t] + ((t >= d) ? A[t - d] : 0);
        B[t] = x;
        __syncthreads();
        int* tmp = A; A = B; B = tmp;
    }
    int excl = A[t] - v;
    B[t] = excl;
    __syncthreads();
    for (int i = t; i < nb; i += 512) {
        uint_t e = E[i];
        int sl = atomicAdd(&B[e >> 16], 1);
        src[base + sl] = (int)(e & 0xffffu);
    }
    int d = (b << BSH) + t;
    if (d < Nn) {
        off[side * Nn + d] = base + excl;
        cnt[side * Nn + d] = v;
    }
}

// ---------------- layer-1 mean aggregation from fp8 table, bf16 mean out ----------------
__global__ __launch_bounds__(256) void k_agg1(
    const uint2* __restrict__ xu8, const uint2* __restrict__ xp8,
    const int* __restrict__ off, const int* __restrict__ cnt,
    const int* __restrict__ src_p, const int* __restrict__ src_u,
    us_t* __restrict__ mu, us_t* __restrict__ mp) {
    int side = blockIdx.y;
    const uint2* X = side ? xp8 : xu8;
    const int* of = off + side * Nn;
    const int* cn = cnt + side * Nn;
    const int* sr = side ? src_u : src_p;
    us_t* out = side ? mp : mu;

    int node = blockIdx.x * 16 + (threadIdx.x >> 4);
    if (node >= Nn) return;
    int l = threadIdx.x & 15;
    int s = of[node], c = cn[node];
    float a0=0.f,a1=0.f,a2=0.f,a3=0.f,a4=0.f,a5=0.f,a6=0.f,a7=0.f;
    int j = 0;
    for (; j + 8 <= c; j += 8) {
        int ss[8];
        #pragma unroll
        for (int q = 0; q < 8; ++q) ss[q] = sr[s + j + q];
        uint2 vv[8];
        #pragma unroll
        for (int q = 0; q < 8; ++q)
            vv[q] = X[(size_t)ss[q] * 16 + l];
        #pragma unroll
        for (int q = 0; q < 8; ++q) {
            f32x2 p0 = __builtin_amdgcn_cvt_pk_f32_fp8((int)vv[q].x, false);
            f32x2 p1 = __builtin_amdgcn_cvt_pk_f32_fp8((int)vv[q].x, true);
            f32x2 p2 = __builtin_amdgcn_cvt_pk_f32_fp8((int)vv[q].y, false);
            f32x2 p3 = __builtin_amdgcn_cvt_pk_f32_fp8((int)vv[q].y, true);
            a0 += p0[0]; a1 += p0[1]; a2 += p1[0]; a3 += p1[1];
            a4 += p2[0]; a5 += p2[1]; a6 += p3[0]; a7 += p3[1];
        }
    }
    for (; j < c; ++j) {
        uint2 v0 = X[(size_t)sr[s + j] * 16 + l];
        f32x2 p0 = __builtin_amdgcn_cvt_pk_f32_fp8((int)v0.x, false);
        f32x2 p1 = __builtin_amdgcn_cvt_pk_f32_fp8((int)v0.x, true);
        f32x2 p2 = __builtin_amdgcn_cvt_pk_f32_fp8((int)v0.y, false);
        f32x2 p3 = __builtin_amdgcn_cvt_pk_f32_fp8((int)v0.y, true);
        a0 += p0[0]; a1 += p0[1]; a2 += p1[0]; a3 += p1[1];
        a4 += p2[0]; a5 += p2[1]; a6 += p3[0]; a7 += p3[1];
    }
    float inv = 1.0f / fmaxf((float)c, 1.0f);
    uint4 o;
    o.x = (uint_t)f2bf(a0 * inv) | ((uint_t)f2bf(a1 * inv) << 16);
    o.y = (uint_t)f2bf(a2 * inv) | ((uint_t)f2bf(a3 * inv) << 16);
    o.z = (uint_t)f2bf(a4 * inv) | ((uint_t)f2bf(a5 * inv) << 16);
    o.w = (uint_t)f2bf(a6 * inv) | ((uint_t)f2bf(a7 * inv) << 16);
    reinterpret_cast<uint4*>(out + (size_t)node * 128)[l] = o;
}

// ---------------- layer-2 mean aggregation (bf16 tbuf), adds into f32 out ----------------
__global__ void k_agg2(const us_t* __restrict__ tu, const us_t* __restrict__ tp,
                       const int* __restrict__ off, const int* __restrict__ cnt,
                       const int* __restrict__ src_p, const int* __restrict__ src_u,
                       float* __restrict__ ou, float* __restrict__ op) {
    int side = blockIdx.y;
    const us_t* T = side ? tp : tu;
    const int* of = off + side * Nn;
    const int* cn = cnt + side * Nn;
    const int* sr = side ? src_u : src_p;
    float* out = side ? op : ou;

    int node = blockIdx.x * 16 + (threadIdx.x >> 4);
    if (node >= Nn) return;
    int sl = threadIdx.x & 15;
    int s = of[node], c = cn[node];
    float a0 = 0.f, a1 = 0.f, a2 = 0.f, a3 = 0.f;
    int j = 0;
    for (; j + 4 <= c; j += 4) {
        int ss[4];
        #pragma unroll
        for (int q = 0; q < 4; ++q) ss[q] = sr[s + j + q];
        uint2 vv[4];
        #pragma unroll
        for (int q = 0; q < 4; ++q)
            vv[q] = reinterpret_cast<const uint2*>(T + (size_t)ss[q] * 64)[sl];
        #pragma unroll
        for (int q = 0; q < 4; ++q) {
            a0 += bflo(vv[q].x); a1 += bfhi(vv[q].x);
            a2 += bflo(vv[q].y); a3 += bfhi(vv[q].y);
        }
    }
    for (; j < c; ++j) {
        int s0 = sr[s + j];
        uint2 v0 = reinterpret_cast<const uint2*>(T + (size_t)s0 * 64)[sl];
        a0 += bflo(v0.x); a1 += bfhi(v0.x); a2 += bflo(v0.y); a3 += bfhi(v0.y);
    }
    float inv = 1.0f / fmaxf((float)c, 1.0f);
    float4* o = reinterpret_cast<float4*>(out + (size_t)node * 64) + sl;
    float4 p = *o;
    p.x += a0 * inv; p.y += a1 * inv; p.z += a2 * inv; p.w += a3 * inv;
    *o = p;
}

// ---------------- layer-1 pipelined GEMM: BM=64, BN=256, K=4x64 chunks ----------------
// 2-phase dbuf pipeline: issue chunk t+1 loads, compute chunk t, vmcnt(0)+barrier.
// NOTE: CP1's argument is the LDS BUFFER index (chunk & 1), not the chunk index.
__global__ __launch_bounds__(256) void k_mm1(
    const us_t* __restrict__ mu, const us_t* __restrict__ mp,
    const us_t* __restrict__ xbu, const us_t* __restrict__ xbp,
    const us_t* __restrict__ wu1l, const us_t* __restrict__ wu1r,
    const us_t* __restrict__ wp1l, const us_t* __restrict__ wp1r,
    const float* __restrict__ bu1, const float* __restrict__ bp1,
    us_t* __restrict__ hu, us_t* __restrict__ hp) {
    __shared__ us_t sA[2][64 * 64];
    __shared__ us_t sW[2][256 * 64];
    int tid = threadIdx.x, lane = tid & 63;
    int wv = tid >> 6, wr = wv >> 1, wc = wv & 1;
    int node_base = blockIdx.x * 64;
    int job = blockIdx.y;

    const us_t* A0 = job ? mp : mu;
    const us_t* A1 = job ? xbu : xbp;
    const us_t* W0 = job ? wp1l : wu1l;
    const us_t* W1 = job ? wp1r : wu1r;
    const float* bias = job ? bp1 : bu1;
    us_t* C = job ? hp : hu;
    const us_t* Ac[4] = {A0, A0 + 64, A1, A1 + 64};   // row stride 128
    const us_t* Wc[4] = {W0, W0 + 64, W1, W1 + 64};   // row stride 128

    f32x4 acc[2][8];
    #pragma unroll
    for (int m = 0; m < 2; ++m)
        #pragma unroll
        for (int n = 0; n < 8; ++n)
            #pragma unroll
            for (int i = 0; i < 4; ++i) acc[m][n][i] = 0.f;

#define ST1(c, b)                                                                   \
    {                                                                               \
        _Pragma("unroll")                                                           \
        for (int ii = 0; ii < 2; ++ii) {                                            \
            int s_ = ii * 256 + tid; int row = s_ >> 3, ks = s_ & 7;                \
            int ksl = ks ^ (row & 7);                                               \
            int gr = node_base + row; if (gr >= Nn) gr = Nn - 1;                    \
            GLOAD(Ac[c] + (size_t)gr * 128 + ksl * 8, &sA[b][(s_ - lane) * 8]);     \
        }                                                                           \
        _Pragma("unroll")                                                           \
        for (int ii = 0; ii < 8; ++ii) {                                            \
            int s_ = ii * 256 + tid; int row = s_ >> 3, ks = s_ & 7;                \
            int ksl = ks ^ (row & 7);                                               \
            GLOAD(Wc[c] + (size_t)row * 128 + ksl * 8, &sW[b][(s_ - lane) * 8]);    \
        }                                                                           \
    }

#define CP1(b)                                                                      \
    {                                                                               \
        _Pragma("unroll")                                                           \
        for (int ks = 0; ks < 2; ++ks) {                                            \
            short8 af[2], bf_[8];                                                   \
            _Pragma("unroll")                                                       \
            for (int m = 0; m < 2; ++m) {                                           \
                int row = wr * 32 + m * 16 + (lane & 15);                           \
                int ksl = (ks * 4 + (lane >> 4)) ^ (row & 7);                       \
                af[m] = *reinterpret_cast<const short8*>(&sA[b][row * 64 + ksl * 8]); \
            }                                                                       \
            _Pragma("unroll")                                                       \
            for (int n = 0; n < 8; ++n) {                                           \
                int row = wc * 128 + n * 16 + (lane & 15);                          \
                int ksl = (ks * 4 + (lane >> 4)) ^ (row & 7);                       \
                bf_[n] = *reinterpret_cast<const short8*>(&sW[b][row * 64 + ksl * 8]); \
            }                                                                       \
            _Pragma("unroll")                                                       \
            for (int m = 0; m < 2; ++m)                                             \
                _Pragma("unroll")                                                   \
                for (int n = 0; n < 8; ++n)                                         \
                    acc[m][n] = __builtin_amdgcn_mfma_f32_16x16x32_bf16(            \
                        af[m], bf_[n], acc[m][n], 0, 0, 0);                         \
        }                                                                           \
    }

    ST1(0, 0);
    asm volatile("s_waitcnt vmcnt(0)" ::: "memory"); __syncthreads();
    ST1(1, 1); CP1(0);
    asm volatile("s_waitcnt vmcnt(0)" ::: "memory"); __syncthreads();
    ST1(2, 0); CP1(1);
    asm volatile("s_waitcnt vmcnt(0)" ::: "memory"); __syncthreads();
    ST1(3, 1); CP1(0);
    asm volatile("s_waitcnt vmcnt(0)" ::: "memory"); __syncthreads();
    CP1(1);

    #pragma unroll
    for (int n = 0; n < 8; ++n) {
        int col = wc * 128 + n * 16 + (lane & 15);
        float bv = bias[col];
        #pragma unroll
        for (int m = 0; m < 2; ++m) {
            int row0 = node_base + wr * 32 + m * 16 + ((lane >> 4) << 2);
            #pragma unroll
            for (int j = 0; j < 4; ++j) {
                int row = row0 + j;
                if (row >= Nn) continue;
                C[(size_t)row * HIDD + col] = f2bf(fmaxf(acc[m][n][j] + bv, 0.f));
            }
        }
    }
#undef ST1
#undef CP1
}

// ---------------- layer-2 pipelined GEMM: BM=64, BN=128 (two fused outputs), K=4x64 ----
// job 0: A=h_u -> [tu (wu2l, bf16) | op (wp2r, f32 + b_p2)]
// job 1: A=h_p -> [tp (wp2l, bf16) | ou (wu2r, f32 + b_u2)]
__global__ __launch_bounds__(256) void k_mm2(
    const us_t* __restrict__ hu, const us_t* __restrict__ hp,
    const us_t* __restrict__ wu2l, const us_t* __restrict__ wu2r,
    const us_t* __restrict__ wp2l, const us_t* __restrict__ wp2r,
    const float* __restrict__ bu2, const float* __restrict__ bp2,
    us_t* __restrict__ tu, us_t* __restrict__ tp,
    float* __restrict__ ou, float* __restrict__ op) {
    __shared__ us_t sA[2][64 * 64];
    __shared__ us_t sW[2][128 * 64];
    int tid = threadIdx.x, lane = tid & 63;
    int wv = tid >> 6, wr = wv >> 1, wc = wv & 1;
    int node_base = blockIdx.x * 64;
    int job = blockIdx.y;

    const us_t* A  = job ? hp : hu;
    const us_t* Wt = job ? wp2l : wu2l;
    const us_t* Wb = job ? wu2r : wp2r;
    const float* bias = job ? bu2 : bp2;
    us_t* T = job ? tp : tu;
    float* O = job ? ou : op;

    f32x4 acc[2][4];
    #pragma unroll
    for (int m = 0; m < 2; ++m)
        #pragma unroll
        for (int n = 0; n < 4; ++n)
            #pragma unroll
            for (int i = 0; i < 4; ++i) acc[m][n][i] = 0.f;

#define ST2(c, b)                                                                   \
    {                                                                               \
        _Pragma("unroll")                                                           \
        for (int ii = 0; ii < 2; ++ii) {                                            \
            int s_ = ii * 256 + tid; int row = s_ >> 3, ks = s_ & 7;                \
            int ksl = ks ^ (row & 7);                                               \
            int gr = node_base + row; if (gr >= Nn) gr = Nn - 1;                    \
            GLOAD(A + (size_t)gr * 256 + (c) * 64 + ksl * 8, &sA[b][(s_ - lane) * 8]); \
        }                                                                           \
        _Pragma("unroll")                                                           \
        for (int ii = 0; ii < 4; ++ii) {                                            \
            int s_ = ii * 256 + tid; int row = s_ >> 3, ks = s_ & 7;                \
            int ksl = ks ^ (row & 7);                                               \
            const us_t* wsrc = (row < 64) ? Wt + (size_t)row * 256                  \
                                          : Wb + (size_t)(row - 64) * 256;          \
            GLOAD(wsrc + (c) * 64 + ksl * 8, &sW[b][(s_ - lane) * 8]);              \
        }                                                                           \
    }

#define CP2(b)                                                                      \
    {                                                                               \
        _Pragma("unroll")                                                           \
        for (int ks = 0; ks < 2; ++ks) {                                            \
            short8 af[2], bf_[4];                                                   \
            _Pragma("unroll")                                                       \
            for (int m = 0; m < 2; ++m) {                                           \
                int row = wr * 32 + m * 16 + (lane & 15);                           \
                int ksl = (ks * 4 + (lane >> 4)) ^ (row & 7);                       \
                af[m] = *reinterpret_cast<const short8*>(&sA[b][row * 64 + ksl * 8]); \
            }                                                                       \
            _Pragma("unroll")                                                       \
            for (int n = 0; n < 4; ++n) {                                           \
                int row = wc * 64 + n * 16 + (lane & 15);                           \
                int ksl = (ks * 4 + (lane >> 4)) ^ (row & 7);                       \
                bf_[n] = *reinterpret_cast<const short8*>(&sW[b][row * 64 + ksl * 8]); \
            }                                                                       \
            _Pragma("unroll")                                                       \
            for (int m = 0; m < 2; ++m)                                             \
                _Pragma("unroll")                                                   \
                for (int n = 0; n < 4; ++n)                                         \
                    acc[m][n] = __builtin_amdgcn_mfma_f32_16x16x32_bf16(            \
                        af[m], bf_[n], acc[m][n], 0, 0, 0);                         \
        }                                                                           \
    }

    ST2(0, 0);
    asm volatile("s_waitcnt vmcnt(0)" ::: "memory"); __syncthreads();
    ST2(1, 1); CP2(0);
    asm volatile("s_waitcnt vmcnt(0)" ::: "memory"); __syncthreads();
    ST2(2, 0); CP2(1);
    asm volatile("s_waitcnt vmcnt(0)" ::: "memory"); __syncthreads();
    ST2(3, 1); CP2(0);
    asm volatile("s_waitcnt vmcnt(0)" ::: "memory"); __syncthreads();
    CP2(1);

    #pragma unroll
    for (int n = 0; n < 4; ++n) {
        int col = wc * 64 + n * 16 + (lane & 15);    // 0..127
        bool top = col < 64;
        int cc = top ? col : col - 64;
        float bv = top ? 0.f : bias[cc];
        #pragma unroll
        for (int m = 0; m < 2; ++m) {
            int row0 = node_base + wr * 32 + m * 16 + ((lane >> 4) << 2);
            #pragma unroll
            for (int j = 0; j < 4; ++j) {
                int row = row0 + j;
                if (row >= Nn) continue;
                float v = acc[m][n][j] + bv;
                if (top) T[(size_t)row * 64 + cc] = f2bf(v);
                else     O[(size_t)row * 64 + cc] = v;
            }
        }
    }
#undef ST2
#undef CP2
}

// ---------------- launch ----------------
extern "C" void kernel_launch(void* const* d_in, const int* in_sizes, int n_in,
                              void* d_out, int out_size, void* d_ws, size_t ws_size,
                              hipStream_t stream) {
    const float* x_user    = (const float*)d_in[0];
    const float* x_product = (const float*)d_in[1];
    const int*   ei        = (const int*)d_in[2];
    const float* w_u1_l = (const float*)d_in[3];
    const float* b_u1   = (const float*)d_in[4];
    const float* w_u1_r = (const float*)d_in[5];
    const float* w_p1_l = (const float*)d_in[6];
    const float* b_p1   = (const float*)d_in[7];
    const float* w_p1_r = (const float*)d_in[8];
    const float* w_u2_l = (const float*)d_in[9];
    const float* b_u2   = (const float*)d_in[10];
    const float* w_u2_r = (const float*)d_in[11];
    const float* w_p2_l = (const float*)d_in[12];
    const float* b_p2   = (const float*)d_in[13];
    const float* w_p2_r = (const float*)d_in[14];

    float* out_u = (float*)d_out;
    float* out_p = out_u + (size_t)Nn * CLSS;

    char* w = (char*)d_ws;
    int* bin_cnt  = (int*)w; w += (size_t)2 * NBIN * 4;
    int* bin_base = (int*)w; w += (size_t)2 * NBIN * 4;
    int* off  = (int*)w;  w += (size_t)2 * Nn * 4;
    int* cnt  = (int*)w;  w += (size_t)2 * Nn * 4;
    int* src_p = (int*)w; w += (size_t)Ee * 4;
    int* src_u = (int*)w; w += (size_t)Ee * 4;
    uint_t* ent_p = (uint_t*)w; w += (size_t)NBIN * BCAP * 4;
    uint_t* ent_u = (uint_t*)w; w += (size_t)NBIN * BCAP * 4;
    uintptr_t a = (uintptr_t)w; a = (a + 255) & ~(uintptr_t)255; w = (char*)a;
    us_t* xbu  = (us_t*)w; w += (size_t)Nn * FIN * 2;
    us_t* xbp  = (us_t*)w; w += (size_t)Nn * FIN * 2;
    uint_t* xf8u = (uint_t*)w; w += (size_t)Nn * FIN;
    uint_t* xf8p = (uint_t*)w; w += (size_t)Nn * FIN;
    us_t* h_u  = (us_t*)w; w += (size_t)Nn * HIDD * 2;
    us_t* h_p  = (us_t*)w; w += (size_t)Nn * HIDD * 2;
    us_t* mean_u = (us_t*)w; w += (size_t)Nn * FIN * 2;
    us_t* mean_p = (us_t*)w; w += (size_t)Nn * FIN * 2;
    us_t* tbuf_u = (us_t*)w; w += (size_t)Nn * CLSS * 2;
    us_t* tbuf_p = (us_t*)w; w += (size_t)Nn * CLSS * 2;
    us_t* wb_u1l = (us_t*)w; w += (size_t)HIDD * FIN * 2;
    us_t* wb_u1r = (us_t*)w; w += (size_t)HIDD * FIN * 2;
    us_t* wb_p1l = (us_t*)w; w += (size_t)HIDD * FIN * 2;
    us_t* wb_p1r = (us_t*)w; w += (size_t)HIDD * FIN * 2;
    us_t* wb_u2l = (us_t*)w; w += (size_t)CLSS * HIDD * 2;
    us_t* wb_u2r = (us_t*)w; w += (size_t)CLSS * HIDD * 2;
    us_t* wb_p2l = (us_t*)w; w += (size_t)CLSS * HIDD * 2;
    us_t* wb_p2r = (us_t*)w; w += (size_t)CLSS * HIDD * 2;

    // conversions + bin_cnt zero
    {
        int n4 = (Nn * FIN) / 4;
        int blocks = (n4 + 255) / 256; if (blocks > 1024) blocks = 1024;
        dim3 g(blocks, 2);
        k_cvtx<<<g, 256, 0, stream>>>(x_user, x_product, xbu, xbp, xf8u, xf8p, n4);
    }
    k_cvtw<<<193, 256, 0, stream>>>(w_u1_l, w_u1_r, w_p1_l, w_p1_r,
                                    w_u2_l, w_u2_r, w_p2_l, w_p2_r,
                                    wb_u1l, wb_u1r, wb_p1l, wb_p1r,
                                    wb_u2l, wb_u2r, wb_p2l, wb_p2r, bin_cnt);

    // binned CSR build
    k_bin<<<NEB, 256, 0, stream>>>(ei, bin_cnt, ent_p, ent_u);
    k_binscan<<<1, 256, 0, stream>>>(bin_cnt, bin_base);
    dim3 gsc(NBIN, 2);
    k_scatter<<<gsc, 512, 0, stream>>>(ent_p, ent_u, bin_cnt, bin_base,
                                       off, cnt, src_p, src_u);

    // ---- layer 1 ----
    dim3 ga1((Nn + 15) / 16, 2);
    k_agg1<<<ga1, 256, 0, stream>>>((const uint2*)xf8u, (const uint2*)xf8p,
                                    off, cnt, src_p, src_u, mean_u, mean_p);
    dim3 g1((Nn + 63) / 64, 2);
    k_mm1<<<g1, 256, 0, stream>>>(mean_u, mean_p, xbu, xbp,
                                  wb_u1l, wb_u1r, wb_p1l, wb_p1r,
                                  b_u1, b_p1, h_u, h_p);

    // ---- layer 2 ----
    dim3 g2((Nn + 63) / 64, 2);
    k_mm2<<<g2, 256, 0, stream>>>(h_u, h_p, wb_u2l, wb_u2r, wb_p2l, wb_p2r,
                                  b_u2, b_p2, tbuf_u, tbuf_p, out_u, out_p);
    dim3 ga2((Nn + 15) / 16, 2);
    k_agg2<<<ga2, 256, 0, stream>>>(tbuf_u, tbuf_p, off, cnt, src_p, src_u, out_u, out_p);
}

// Round 9
// 190.917 us; speedup vs baseline: 1.1700x; 1.1700x over previous
//
#include <hip/hip_runtime.h>
#include <stdint.h>

#define Nn 50000
#define Ee 800000
#define FIN 128
#define HIDD 256
#define CLSS 64

#define NBIN 98          // ceil(50000 / 512)
#define BSH 9
#define BINSZ 512
#define BCAP 16384
#define EPB 2048
#define NEB ((Ee + EPB - 1) / EPB)   // 391

#define MT_TOT 782       // ceil(50000/64)
#define GX 112           // M-group blocks per job; each handles ceil(782/112)=7 tiles

typedef unsigned int uint_t;
typedef unsigned short us_t;
typedef __attribute__((ext_vector_type(8))) short short8;
typedef __attribute__((ext_vector_type(4))) float f32x4;
typedef __attribute__((ext_vector_type(2))) float f32x2;

__device__ inline float bflo(uint_t v) { union { uint_t u; float f; } c; c.u = v << 16; return c.f; }
__device__ inline float bfhi(uint_t v) { union { uint_t u; float f; } c; c.u = v & 0xffff0000u; return c.f; }
__device__ inline us_t f2bf(float f) {
    union { float f; uint_t u; } c; c.f = f;
    uint_t u = c.u;
    u += 0x7fffu + ((u >> 16) & 1u);
    return (us_t)(u >> 16);
}

#define GLOAD(gp, lp)                                                      \
    __builtin_amdgcn_global_load_lds(                                      \
        (const __attribute__((address_space(1))) unsigned int*)(gp),       \
        (__attribute__((address_space(3))) unsigned int*)(lp), 16, 0, 0)

// ---------------- x convert: fp8 (gather) + bf16 into comb back-half ----------------
// side0: x_user  -> xf8u, and bf16 -> cp[node][128:256]  (cp = [mean_p | x_user])
// side1: x_prod  -> xf8p, and bf16 -> cu[node][128:256]  (cu = [mean_u | x_prod])
__global__ void k_cvtx(const float* __restrict__ xu, const float* __restrict__ xp,
                       us_t* __restrict__ cu, us_t* __restrict__ cp,
                       uint_t* __restrict__ f8u, uint_t* __restrict__ f8p, int n4) {
    int side = blockIdx.y;
    const float* in = side ? xp : xu;
    us_t* comb = side ? cu : cp;
    uint_t* o8 = side ? f8p : f8u;
    int i = blockIdx.x * 256 + threadIdx.x;
    int stride = gridDim.x * 256;
    for (; i < n4; i += stride) {
        float4 v = reinterpret_cast<const float4*>(in)[i];
        ushort4 o;
        o.x = f2bf(v.x); o.y = f2bf(v.y); o.z = f2bf(v.z); o.w = f2bf(v.w);
        int node = i >> 5;            // 32 vec4 per 128-col row
        int col = (i & 31) * 4;
        *reinterpret_cast<ushort4*>(comb + (size_t)node * 256 + 128 + col) = o;
        int pk = __builtin_amdgcn_cvt_pk_fp8_f32(v.x, v.y, 0, false);
        pk = __builtin_amdgcn_cvt_pk_fp8_f32(v.z, v.w, pk, true);
        o8[i] = (uint_t)pk;
    }
}

// ---------------- weight convert into K-concat / row-stacked layouts + bin_cnt zero ----
// wc10[o][0:128]=wu1l, [128:256]=wu1r ; wc11: wp1l|wp1r
// wc20 rows0-63=wu2l, rows64-127=wp2r ; wc21 rows0-63=wp2l, rows64-127=wu2r
__global__ void k_cvtw(const float* __restrict__ w1, const float* __restrict__ w2,
                       const float* __restrict__ w3, const float* __restrict__ w4,
                       const float* __restrict__ w5, const float* __restrict__ w6,
                       const float* __restrict__ w7, const float* __restrict__ w8,
                       us_t* __restrict__ wc10, us_t* __restrict__ wc11,
                       us_t* __restrict__ wc20, us_t* __restrict__ wc21,
                       int* __restrict__ bin_cnt) {
    if (blockIdx.x == 192) {
        int t = threadIdx.x;
        if (t < 2 * NBIN) bin_cnt[t] = 0;
        return;
    }
    int i = blockIdx.x * 256 + threadIdx.x;
    const float* wp; us_t* dst;
    if (i < 32768) {
        int seg = i >> 13; int loc = i & 8191;
        int row = loc >> 5, col = (loc & 31) * 4;
        switch (seg) {
            case 0: wp = w1; dst = wc10 + (size_t)row * 256 + col; break;
            case 1: wp = w2; dst = wc10 + (size_t)row * 256 + 128 + col; break;
            case 2: wp = w3; dst = wc11 + (size_t)row * 256 + col; break;
            default: wp = w4; dst = wc11 + (size_t)row * 256 + 128 + col; break;
        }
        float4 v = reinterpret_cast<const float4*>(wp)[loc];
        ushort4 o;
        o.x = f2bf(v.x); o.y = f2bf(v.y); o.z = f2bf(v.z); o.w = f2bf(v.w);
        *reinterpret_cast<ushort4*>(dst) = o;
    } else {
        int j = i - 32768;
        int seg = j >> 12; int loc = j & 4095;   // 4096 vec4 = 16384 elems
        switch (seg) {
            case 0: wp = w5; dst = wc20; break;                 // wu2l
            case 1: wp = w6; dst = wc21 + 64 * 256; break;      // wu2r
            case 2: wp = w7; dst = wc21; break;                 // wp2l
            default: wp = w8; dst = wc20 + 64 * 256; break;     // wp2r
        }
        float4 v = reinterpret_cast<const float4*>(wp)[loc];
        ushort4 o;
        o.x = f2bf(v.x); o.y = f2bf(v.y); o.z = f2bf(v.z); o.w = f2bf(v.w);
        reinterpret_cast<ushort4*>(dst)[loc] = o;
    }
}

// ---------------- binned CSR build ----------------
__global__ __launch_bounds__(256) void k_bin(const int* __restrict__ ei,
                                             int* __restrict__ bin_cnt,
                                             uint_t* __restrict__ ent_p,
                                             uint_t* __restrict__ ent_u) {
    __shared__ int hist[2 * NBIN];
    __shared__ int base[2 * NBIN];
    int tid = threadIdx.x;
    int e0 = blockIdx.x * EPB;
    int n = Ee - e0; if (n > EPB) n = EPB;

    for (int i = tid; i < 2 * NBIN; i += 256) hist[i] = 0;
    __syncthreads();
    for (int i = tid; i < n; i += 256) {
        int u = ei[e0 + i], p = ei[Ee + e0 + i];
        atomicAdd(&hist[p >> BSH], 1);
        atomicAdd(&hist[NBIN + (u >> BSH)], 1);
    }
    __syncthreads();
    for (int i = tid; i < 2 * NBIN; i += 256) {
        int c = hist[i];
        base[i] = c ? atomicAdd(&bin_cnt[i], c) : 0;
    }
    __syncthreads();
    for (int i = tid; i < 2 * NBIN; i += 256) hist[i] = base[i];
    __syncthreads();
    for (int i = tid; i < n; i += 256) {
        int u = ei[e0 + i], p = ei[Ee + e0 + i];
        int bp = p >> BSH, bu = u >> BSH;
        int rp = atomicAdd(&hist[bp], 1);
        if (rp < BCAP)
            ent_p[(size_t)bp * BCAP + rp] = ((uint_t)(p & (BINSZ - 1)) << 16) | (uint_t)u;
        int ru = atomicAdd(&hist[NBIN + bu], 1);
        if (ru < BCAP)
            ent_u[(size_t)bu * BCAP + ru] = ((uint_t)(u & (BINSZ - 1)) << 16) | (uint_t)p;
    }
}

__global__ void k_binscan(const int* __restrict__ bin_cnt, int* __restrict__ bin_base) {
    __shared__ int buf[2][128];
    int t = threadIdx.x;
    int side = t >> 7, i = t & 127;
    int v = 0;
    if (i < NBIN) { v = bin_cnt[side * NBIN + i]; if (v > BCAP) v = BCAP; }
    buf[side][i] = v;
    __syncthreads();
    #pragma unroll
    for (int d = 1; d < 128; d <<= 1) {
        int x = (i >= d) ? buf[side][i - d] : 0;
        __syncthreads();
        buf[side][i] += x;
        __syncthreads();
    }
    if (i < NBIN) bin_base[side * NBIN + i] = buf[side][i] - v;
}

__global__ __launch_bounds__(512) void k_scatter(
    const uint_t* __restrict__ ent_p, const uint_t* __restrict__ ent_u,
    const int* __restrict__ bin_cnt, const int* __restrict__ bin_base,
    int* __restrict__ off, int* __restrict__ cnt,
    int* __restrict__ src_p, int* __restrict__ src_u) {
    __shared__ int ca[BINSZ];
    __shared__ int cb[BINSZ];
    int side = blockIdx.y, b = blockIdx.x, t = threadIdx.x;
    const uint_t* E = (side ? ent_u : ent_p) + (size_t)b * BCAP;
    int* src = side ? src_u : src_p;
    int nb = bin_cnt[side * NBIN + b]; if (nb > BCAP) nb = BCAP;
    int base = bin_base[side * NBIN + b];

    ca[t] = 0;
    __syncthreads();
    for (int i = t; i < nb; i += 512)
        atomicAdd(&ca[E[i] >> 16], 1);
    __syncthreads();
    int v = ca[t];
    int* A = ca; int* B = cb;
    #pragma unroll
    for (int d = 1; d < BINSZ; d <<= 1) {
        int x = A[t] + ((t >= d) ? A[t - d] : 0);
        B[t] = x;
        __syncthreads();
        int* tmp = A; A = B; B = tmp;
    }
    int excl = A[t] - v;
    B[t] = excl;
    __syncthreads();
    for (int i = t; i < nb; i += 512) {
        uint_t e = E[i];
        int sl = atomicAdd(&B[e >> 16], 1);
        src[base + sl] = (int)(e & 0xffffu);
    }
    int d = (b << BSH) + t;
    if (d < Nn) {
        off[side * Nn + d] = base + excl;
        cnt[side * Nn + d] = v;
    }
}

// ---------------- layer-1 mean aggregation from fp8 table -> comb front half ----------
__global__ __launch_bounds__(256) void k_agg1(
    const uint2* __restrict__ xu8, const uint2* __restrict__ xp8,
    const int* __restrict__ off, const int* __restrict__ cnt,
    const int* __restrict__ src_p, const int* __restrict__ src_u,
    us_t* __restrict__ cu, us_t* __restrict__ cp) {
    int side = blockIdx.y;
    const uint2* X = side ? xp8 : xu8;
    const int* of = off + side * Nn;
    const int* cn = cnt + side * Nn;
    const int* sr = side ? src_u : src_p;
    us_t* out = side ? cp : cu;     // side0: mean of x_user -> cu front

    int node = blockIdx.x * 16 + (threadIdx.x >> 4);
    if (node >= Nn) return;
    int l = threadIdx.x & 15;
    int s = of[node], c = cn[node];
    float a0=0.f,a1=0.f,a2=0.f,a3=0.f,a4=0.f,a5=0.f,a6=0.f,a7=0.f;
    int j = 0;
    for (; j + 8 <= c; j += 8) {
        int ss[8];
        #pragma unroll
        for (int q = 0; q < 8; ++q) ss[q] = sr[s + j + q];
        uint2 vv[8];
        #pragma unroll
        for (int q = 0; q < 8; ++q)
            vv[q] = X[(size_t)ss[q] * 16 + l];
        #pragma unroll
        for (int q = 0; q < 8; ++q) {
            f32x2 p0 = __builtin_amdgcn_cvt_pk_f32_fp8((int)vv[q].x, false);
            f32x2 p1 = __builtin_amdgcn_cvt_pk_f32_fp8((int)vv[q].x, true);
            f32x2 p2 = __builtin_amdgcn_cvt_pk_f32_fp8((int)vv[q].y, false);
            f32x2 p3 = __builtin_amdgcn_cvt_pk_f32_fp8((int)vv[q].y, true);
            a0 += p0[0]; a1 += p0[1]; a2 += p1[0]; a3 += p1[1];
            a4 += p2[0]; a5 += p2[1]; a6 += p3[0]; a7 += p3[1];
        }
    }
    for (; j < c; ++j) {
        uint2 v0 = X[(size_t)sr[s + j] * 16 + l];
        f32x2 p0 = __builtin_amdgcn_cvt_pk_f32_fp8((int)v0.x, false);
        f32x2 p1 = __builtin_amdgcn_cvt_pk_f32_fp8((int)v0.x, true);
        f32x2 p2 = __builtin_amdgcn_cvt_pk_f32_fp8((int)v0.y, false);
        f32x2 p3 = __builtin_amdgcn_cvt_pk_f32_fp8((int)v0.y, true);
        a0 += p0[0]; a1 += p0[1]; a2 += p1[0]; a3 += p1[1];
        a4 += p2[0]; a5 += p2[1]; a6 += p3[0]; a7 += p3[1];
    }
    float inv = 1.0f / fmaxf((float)c, 1.0f);
    uint4 o;
    o.x = (uint_t)f2bf(a0 * inv) | ((uint_t)f2bf(a1 * inv) << 16);
    o.y = (uint_t)f2bf(a2 * inv) | ((uint_t)f2bf(a3 * inv) << 16);
    o.z = (uint_t)f2bf(a4 * inv) | ((uint_t)f2bf(a5 * inv) << 16);
    o.w = (uint_t)f2bf(a6 * inv) | ((uint_t)f2bf(a7 * inv) << 16);
    reinterpret_cast<uint4*>(out + (size_t)node * 256)[l] = o;   // cols l*8..l*8+7
}

// ---------------- layer-2 mean aggregation (bf16 tbuf), adds into f32 out ----------------
__global__ void k_agg2(const us_t* __restrict__ tu, const us_t* __restrict__ tp,
                       const int* __restrict__ off, const int* __restrict__ cnt,
                       const int* __restrict__ src_p, const int* __restrict__ src_u,
                       float* __restrict__ ou, float* __restrict__ op) {
    int side = blockIdx.y;
    const us_t* T = side ? tp : tu;
    const int* of = off + side * Nn;
    const int* cn = cnt + side * Nn;
    const int* sr = side ? src_u : src_p;
    float* out = side ? op : ou;

    int node = blockIdx.x * 16 + (threadIdx.x >> 4);
    if (node >= Nn) return;
    int sl = threadIdx.x & 15;
    int s = of[node], c = cn[node];
    float a0 = 0.f, a1 = 0.f, a2 = 0.f, a3 = 0.f;
    int j = 0;
    for (; j + 4 <= c; j += 4) {
        int ss[4];
        #pragma unroll
        for (int q = 0; q < 4; ++q) ss[q] = sr[s + j + q];
        uint2 vv[4];
        #pragma unroll
        for (int q = 0; q < 4; ++q)
            vv[q] = reinterpret_cast<const uint2*>(T + (size_t)ss[q] * 64)[sl];
        #pragma unroll
        for (int q = 0; q < 4; ++q) {
            a0 += bflo(vv[q].x); a1 += bfhi(vv[q].x);
            a2 += bflo(vv[q].y); a3 += bfhi(vv[q].y);
        }
    }
    for (; j < c; ++j) {
        int s0 = sr[s + j];
        uint2 v0 = reinterpret_cast<const uint2*>(T + (size_t)s0 * 64)[sl];
        a0 += bflo(v0.x); a1 += bfhi(v0.x); a2 += bflo(v0.y); a3 += bfhi(v0.y);
    }
    float inv = 1.0f / fmaxf((float)c, 1.0f);
    float4* o = reinterpret_cast<float4*>(out + (size_t)node * 64) + sl;
    float4 p = *o;
    p.x += a0 * inv; p.y += a1 * inv; p.z += a2 * inv; p.w += a3 * inv;
    *o = p;
}

// ---------------- A-tile stage: 64 rows x 256 K bf16 = 32 KB, XOR-swizzled ----------------
#define STAGE_A(Ag, mt, b)                                                          \
    {                                                                               \
        int base_ = (mt) * 64;                                                      \
        _Pragma("unroll")                                                           \
        for (int ii = 0; ii < 4; ++ii) {                                            \
            int s_ = ii * 512 + tid;                                                \
            int row_ = s_ >> 5, ks_ = s_ & 31;                                      \
            int ksl_ = ks_ ^ (row_ & 7);                                            \
            int gr_ = base_ + row_; if (gr_ >= Nn) gr_ = Nn - 1;                    \
            GLOAD((Ag) + (size_t)gr_ * 256 + ksl_ * 8, &sA[b][(s_ - lane) * 8]);    \
        }                                                                           \
    }

// ---------------- layer-1 GEMM: M=50000, K=256, N=256; W in registers ----------------
// 512 thr = 8 waves (2M x 4N); each wave: 64 out-cols of W as 32 short8 frags.
// A staged in LDS dbuf with counted vmcnt(4). Each block walks M with stride GX.
__global__ __launch_bounds__(512) void k_mm1(
    const us_t* __restrict__ cu, const us_t* __restrict__ cp,
    const us_t* __restrict__ wc10, const us_t* __restrict__ wc11,
    const float* __restrict__ bu1, const float* __restrict__ bp1,
    us_t* __restrict__ hu, us_t* __restrict__ hp) {
    __shared__ us_t sA[2][64 * 256];
    int tid = threadIdx.x, lane = tid & 63;
    int wv = tid >> 6, wr = wv >> 2, wc = wv & 3;
    int job = blockIdx.y;
    const us_t* Ag = job ? cp : cu;
    const us_t* W = job ? wc11 : wc10;
    const float* bias = job ? bp1 : bu1;
    us_t* C = job ? hp : hu;

    // preload W frags (64 cols x K=256 per wave)
    short8 wf[4][8];
    #pragma unroll
    for (int n = 0; n < 4; ++n)
        #pragma unroll
        for (int ks = 0; ks < 8; ++ks) {
            int col = wc * 64 + n * 16 + (lane & 15);
            wf[n][ks] = *reinterpret_cast<const short8*>(
                W + (size_t)col * 256 + ks * 32 + (lane >> 4) * 8);
        }
    float bv[4];
    #pragma unroll
    for (int n = 0; n < 4; ++n) bv[n] = bias[wc * 64 + n * 16 + (lane & 15)];

    int bx = blockIdx.x;
    int NT = (MT_TOT - 1 - bx) / GX + 1;
    STAGE_A(Ag, bx, 0);
    for (int t = 0; t < NT; ++t) {
        int mt = bx + t * GX;
        if (t + 1 < NT) {
            STAGE_A(Ag, bx + (t + 1) * GX, (t + 1) & 1);
            asm volatile("s_waitcnt vmcnt(4)" ::: "memory");
        } else {
            asm volatile("s_waitcnt vmcnt(0)" ::: "memory");
        }
        __syncthreads();
        const us_t* sAc = sA[t & 1];

        f32x4 acc[2][4];
        #pragma unroll
        for (int m = 0; m < 2; ++m)
            #pragma unroll
            for (int n = 0; n < 4; ++n)
                #pragma unroll
                for (int i = 0; i < 4; ++i) acc[m][n][i] = 0.f;

        #pragma unroll
        for (int ks = 0; ks < 8; ++ks) {
            short8 af[2];
            #pragma unroll
            for (int m = 0; m < 2; ++m) {
                int row = wr * 32 + m * 16 + (lane & 15);
                int sl = (ks * 4 + (lane >> 4)) ^ (row & 7);
                af[m] = *reinterpret_cast<const short8*>(&sAc[row * 256 + sl * 8]);
            }
            #pragma unroll
            for (int m = 0; m < 2; ++m)
                #pragma unroll
                for (int n = 0; n < 4; ++n)
                    acc[m][n] = __builtin_amdgcn_mfma_f32_16x16x32_bf16(
                        af[m], wf[n][ks], acc[m][n], 0, 0, 0);
        }

        int mbase = mt * 64;
        #pragma unroll
        for (int n = 0; n < 4; ++n) {
            int col = wc * 64 + n * 16 + (lane & 15);
            #pragma unroll
            for (int m = 0; m < 2; ++m) {
                int row0 = mbase + wr * 32 + m * 16 + ((lane >> 4) << 2);
                #pragma unroll
                for (int j = 0; j < 4; ++j) {
                    int row = row0 + j;
                    if (row < Nn)
                        C[(size_t)row * HIDD + col] =
                            f2bf(fmaxf(acc[m][n][j] + bv[n], 0.f));
                }
            }
        }
        __syncthreads();
    }
}

// ---------------- layer-2 GEMM: M=50000, K=256, N=128; W in registers ----------------
// job0: A=h_u, W=wc20 -> cols0-63: tu (bf16), cols64-127: op (f32 + b_p2)
// job1: A=h_p, W=wc21 -> cols0-63: tp (bf16), cols64-127: ou (f32 + b_u2)
__global__ __launch_bounds__(512) void k_mm2(
    const us_t* __restrict__ hu, const us_t* __restrict__ hp,
    const us_t* __restrict__ wc20, const us_t* __restrict__ wc21,
    const float* __restrict__ bu2, const float* __restrict__ bp2,
    us_t* __restrict__ tu, us_t* __restrict__ tp,
    float* __restrict__ ou, float* __restrict__ op) {
    __shared__ us_t sA[2][64 * 256];
    int tid = threadIdx.x, lane = tid & 63;
    int wv = tid >> 6, wr = wv >> 2, wc = wv & 3;
    int job = blockIdx.y;
    const us_t* Ag = job ? hp : hu;
    const us_t* W = job ? wc21 : wc20;
    const float* bias = job ? bu2 : bp2;
    us_t* T = job ? tp : tu;
    float* O = job ? ou : op;

    short8 wf[2][8];
    #pragma unroll
    for (int n = 0; n < 2; ++n)
        #pragma unroll
        for (int ks = 0; ks < 8; ++ks) {
            int col = wc * 32 + n * 16 + (lane & 15);
            wf[n][ks] = *reinterpret_cast<const short8*>(
                W + (size_t)col * 256 + ks * 32 + (lane >> 4) * 8);
        }
    float bv[2];
    #pragma unroll
    for (int n = 0; n < 2; ++n) {
        int col = wc * 32 + n * 16 + (lane & 15);
        bv[n] = (col >= 64) ? bias[col - 64] : 0.f;
    }

    int bx = blockIdx.x;
    int NT = (MT_TOT - 1 - bx) / GX + 1;
    STAGE_A(Ag, bx, 0);
    for (int t = 0; t < NT; ++t) {
        int mt = bx + t * GX;
        if (t + 1 < NT) {
            STAGE_A(Ag, bx + (t + 1) * GX, (t + 1) & 1);
            asm volatile("s_waitcnt vmcnt(4)" ::: "memory");
        } else {
            asm volatile("s_waitcnt vmcnt(0)" ::: "memory");
        }
        __syncthreads();
        const us_t* sAc = sA[t & 1];

        f32x4 acc[2][2];
        #pragma unroll
        for (int m = 0; m < 2; ++m)
            #pragma unroll
            for (int n = 0; n < 2; ++n)
                #pragma unroll
                for (int i = 0; i < 4; ++i) acc[m][n][i] = 0.f;

        #pragma unroll
        for (int ks = 0; ks < 8; ++ks) {
            short8 af[2];
            #pragma unroll
            for (int m = 0; m < 2; ++m) {
                int row = wr * 32 + m * 16 + (lane & 15);
                int sl = (ks * 4 + (lane >> 4)) ^ (row & 7);
                af[m] = *reinterpret_cast<const short8*>(&sAc[row * 256 + sl * 8]);
            }
            #pragma unroll
            for (int m = 0; m < 2; ++m)
                #pragma unroll
                for (int n = 0; n < 2; ++n)
                    acc[m][n] = __builtin_amdgcn_mfma_f32_16x16x32_bf16(
                        af[m], wf[n][ks], acc[m][n], 0, 0, 0);
        }

        int mbase = mt * 64;
        #pragma unroll
        for (int n = 0; n < 2; ++n) {
            int col = wc * 32 + n * 16 + (lane & 15);
            bool top = col < 64;
            int cc = top ? col : col - 64;
            #pragma unroll
            for (int m = 0; m < 2; ++m) {
                int row0 = mbase + wr * 32 + m * 16 + ((lane >> 4) << 2);
                #pragma unroll
                for (int j = 0; j < 4; ++j) {
                    int row = row0 + j;
                    if (row >= Nn) continue;
                    float v = acc[m][n][j] + bv[n];
                    if (top) T[(size_t)row * 64 + cc] = f2bf(v);
                    else     O[(size_t)row * 64 + cc] = v;
                }
            }
        }
        __syncthreads();
    }
}

// ---------------- launch ----------------
extern "C" void kernel_launch(void* const* d_in, const int* in_sizes, int n_in,
                              void* d_out, int out_size, void* d_ws, size_t ws_size,
                              hipStream_t stream) {
    const float* x_user    = (const float*)d_in[0];
    const float* x_product = (const float*)d_in[1];
    const int*   ei        = (const int*)d_in[2];
    const float* w_u1_l = (const float*)d_in[3];
    const float* b_u1   = (const float*)d_in[4];
    const float* w_u1_r = (const float*)d_in[5];
    const float* w_p1_l = (const float*)d_in[6];
    const float* b_p1   = (const float*)d_in[7];
    const float* w_p1_r = (const float*)d_in[8];
    const float* w_u2_l = (const float*)d_in[9];
    const float* b_u2   = (const float*)d_in[10];
    const float* w_u2_r = (const float*)d_in[11];
    const float* w_p2_l = (const float*)d_in[12];
    const float* b_p2   = (const float*)d_in[13];
    const float* w_p2_r = (const float*)d_in[14];

    float* out_u = (float*)d_out;
    float* out_p = out_u + (size_t)Nn * CLSS;

    char* w = (char*)d_ws;
    int* bin_cnt  = (int*)w; w += (size_t)2 * NBIN * 4;
    int* bin_base = (int*)w; w += (size_t)2 * NBIN * 4;
    int* off  = (int*)w;  w += (size_t)2 * Nn * 4;
    int* cnt  = (int*)w;  w += (size_t)2 * Nn * 4;
    int* src_p = (int*)w; w += (size_t)Ee * 4;
    int* src_u = (int*)w; w += (size_t)Ee * 4;
    uint_t* ent_p = (uint_t*)w; w += (size_t)NBIN * BCAP * 4;
    uint_t* ent_u = (uint_t*)w; w += (size_t)NBIN * BCAP * 4;
    uintptr_t a = (uintptr_t)w; a = (a + 255) & ~(uintptr_t)255; w = (char*)a;
    us_t* cu   = (us_t*)w; w += (size_t)Nn * 256 * 2;   // [mean_u | x_prod]
    us_t* cp   = (us_t*)w; w += (size_t)Nn * 256 * 2;   // [mean_p | x_user]
    uint_t* xf8u = (uint_t*)w; w += (size_t)Nn * FIN;
    uint_t* xf8p = (uint_t*)w; w += (size_t)Nn * FIN;
    us_t* h_u  = (us_t*)w; w += (size_t)Nn * HIDD * 2;
    us_t* h_p  = (us_t*)w; w += (size_t)Nn * HIDD * 2;
    us_t* tbuf_u = (us_t*)w; w += (size_t)Nn * CLSS * 2;
    us_t* tbuf_p = (us_t*)w; w += (size_t)Nn * CLSS * 2;
    us_t* wc10 = (us_t*)w; w += (size_t)256 * 256 * 2;
    us_t* wc11 = (us_t*)w; w += (size_t)256 * 256 * 2;
    us_t* wc20 = (us_t*)w; w += (size_t)128 * 256 * 2;
    us_t* wc21 = (us_t*)w; w += (size_t)128 * 256 * 2;

    // conversions + bin_cnt zero
    {
        int n4 = (Nn * FIN) / 4;
        int blocks = (n4 + 255) / 256; if (blocks > 1024) blocks = 1024;
        dim3 g(blocks, 2);
        k_cvtx<<<g, 256, 0, stream>>>(x_user, x_product, cu, cp, xf8u, xf8p, n4);
    }
    k_cvtw<<<193, 256, 0, stream>>>(w_u1_l, w_u1_r, w_p1_l, w_p1_r,
                                    w_u2_l, w_u2_r, w_p2_l, w_p2_r,
                                    wc10, wc11, wc20, wc21, bin_cnt);

    // binned CSR build
    k_bin<<<NEB, 256, 0, stream>>>(ei, bin_cnt, ent_p, ent_u);
    k_binscan<<<1, 256, 0, stream>>>(bin_cnt, bin_base);
    dim3 gsc(NBIN, 2);
    k_scatter<<<gsc, 512, 0, stream>>>(ent_p, ent_u, bin_cnt, bin_base,
                                       off, cnt, src_p, src_u);

    // ---- layer 1 ----
    dim3 ga1((Nn + 15) / 16, 2);
    k_agg1<<<ga1, 256, 0, stream>>>((const uint2*)xf8u, (const uint2*)xf8p,
                                    off, cnt, src_p, src_u, cu, cp);
    dim3 g1(GX, 2);
    k_mm1<<<g1, 512, 0, stream>>>(cu, cp, wc10, wc11, b_u1, b_p1, h_u, h_p);

    // ---- layer 2 ----
    dim3 g2(GX, 2);
    k_mm2<<<g2, 512, 0, stream>>>(h_u, h_p, wc20, wc21, b_u2, b_p2,
                                  tbuf_u, tbuf_p, out_u, out_p);
    dim3 ga2((Nn + 15) / 16, 2);
    k_agg2<<<ga2, 256, 0, stream>>>(tbuf_u, tbuf_p, off, cnt, src_p, src_u, out_u, out_p);
}

// Round 10
// 187.426 us; speedup vs baseline: 1.1918x; 1.0186x over previous
//
#include <hip/hip_runtime.h>
#include <stdint.h>

#define Nn 50000
#define Ee 800000
#define FIN 128
#define HIDD 256
#define CLSS 64

#define NBIN 98          // ceil(50000 / 512)
#define BSH 9
#define BINSZ 512
#define BCAP 16384
#define EPB 2048
#define NEB ((Ee + EPB - 1) / EPB)   // 391

#define MT_TOT 782       // ceil(50000/64)
#define GX 112           // M-group blocks per job

typedef unsigned int uint_t;
typedef unsigned short us_t;
typedef __attribute__((ext_vector_type(8))) short short8;
typedef __attribute__((ext_vector_type(4))) float f32x4;
typedef __attribute__((ext_vector_type(2))) float f32x2;

__device__ inline float bflo(uint_t v) { union { uint_t u; float f; } c; c.u = v << 16; return c.f; }
__device__ inline float bfhi(uint_t v) { union { uint_t u; float f; } c; c.u = v & 0xffff0000u; return c.f; }
__device__ inline us_t f2bf(float f) {
    union { float f; uint_t u; } c; c.f = f;
    uint_t u = c.u;
    u += 0x7fffu + ((u >> 16) & 1u);
    return (us_t)(u >> 16);
}

#define GLOAD(gp, lp)                                                      \
    __builtin_amdgcn_global_load_lds(                                      \
        (const __attribute__((address_space(1))) unsigned int*)(gp),       \
        (__attribute__((address_space(3))) unsigned int*)(lp), 16, 0, 0)

// ---------------- x convert: fp8 (gather) + bf16 into comb back-half ----------------
__global__ void k_cvtx(const float* __restrict__ xu, const float* __restrict__ xp,
                       us_t* __restrict__ cu, us_t* __restrict__ cp,
                       uint_t* __restrict__ f8u, uint_t* __restrict__ f8p, int n4) {
    int side = blockIdx.y;
    const float* in = side ? xp : xu;
    us_t* comb = side ? cu : cp;
    uint_t* o8 = side ? f8p : f8u;
    int i = blockIdx.x * 256 + threadIdx.x;
    int stride = gridDim.x * 256;
    for (; i < n4; i += stride) {
        float4 v = reinterpret_cast<const float4*>(in)[i];
        ushort4 o;
        o.x = f2bf(v.x); o.y = f2bf(v.y); o.z = f2bf(v.z); o.w = f2bf(v.w);
        int node = i >> 5;
        int col = (i & 31) * 4;
        *reinterpret_cast<ushort4*>(comb + (size_t)node * 256 + 128 + col) = o;
        int pk = __builtin_amdgcn_cvt_pk_fp8_f32(v.x, v.y, 0, false);
        pk = __builtin_amdgcn_cvt_pk_fp8_f32(v.z, v.w, pk, true);
        o8[i] = (uint_t)pk;
    }
}

// ---------------- weight convert + bin_cnt zero ----------------
__global__ void k_cvtw(const float* __restrict__ w1, const float* __restrict__ w2,
                       const float* __restrict__ w3, const float* __restrict__ w4,
                       const float* __restrict__ w5, const float* __restrict__ w6,
                       const float* __restrict__ w7, const float* __restrict__ w8,
                       us_t* __restrict__ wc10, us_t* __restrict__ wc11,
                       us_t* __restrict__ wc20, us_t* __restrict__ wc21,
                       int* __restrict__ bin_cnt) {
    if (blockIdx.x == 192) {
        int t = threadIdx.x;
        if (t < 2 * NBIN) bin_cnt[t] = 0;
        return;
    }
    int i = blockIdx.x * 256 + threadIdx.x;
    const float* wp; us_t* dst;
    if (i < 32768) {
        int seg = i >> 13; int loc = i & 8191;
        int row = loc >> 5, col = (loc & 31) * 4;
        switch (seg) {
            case 0: wp = w1; dst = wc10 + (size_t)row * 256 + col; break;
            case 1: wp = w2; dst = wc10 + (size_t)row * 256 + 128 + col; break;
            case 2: wp = w3; dst = wc11 + (size_t)row * 256 + col; break;
            default: wp = w4; dst = wc11 + (size_t)row * 256 + 128 + col; break;
        }
        float4 v = reinterpret_cast<const float4*>(wp)[loc];
        ushort4 o;
        o.x = f2bf(v.x); o.y = f2bf(v.y); o.z = f2bf(v.z); o.w = f2bf(v.w);
        *reinterpret_cast<ushort4*>(dst) = o;
    } else {
        int j = i - 32768;
        int seg = j >> 12; int loc = j & 4095;
        switch (seg) {
            case 0: wp = w5; dst = wc20; break;
            case 1: wp = w6; dst = wc21 + 64 * 256; break;
            case 2: wp = w7; dst = wc21; break;
            default: wp = w8; dst = wc20 + 64 * 256; break;
        }
        float4 v = reinterpret_cast<const float4*>(wp)[loc];
        ushort4 o;
        o.x = f2bf(v.x); o.y = f2bf(v.y); o.z = f2bf(v.z); o.w = f2bf(v.w);
        reinterpret_cast<ushort4*>(dst)[loc] = o;
    }
}

// ---------------- binned CSR build ----------------
__global__ __launch_bounds__(256) void k_bin(const int* __restrict__ ei,
                                             int* __restrict__ bin_cnt,
                                             uint_t* __restrict__ ent_p,
                                             uint_t* __restrict__ ent_u) {
    __shared__ int hist[2 * NBIN];
    __shared__ int base[2 * NBIN];
    int tid = threadIdx.x;
    int e0 = blockIdx.x * EPB;
    int n = Ee - e0; if (n > EPB) n = EPB;

    for (int i = tid; i < 2 * NBIN; i += 256) hist[i] = 0;
    __syncthreads();
    for (int i = tid; i < n; i += 256) {
        int u = ei[e0 + i], p = ei[Ee + e0 + i];
        atomicAdd(&hist[p >> BSH], 1);
        atomicAdd(&hist[NBIN + (u >> BSH)], 1);
    }
    __syncthreads();
    for (int i = tid; i < 2 * NBIN; i += 256) {
        int c = hist[i];
        base[i] = c ? atomicAdd(&bin_cnt[i], c) : 0;
    }
    __syncthreads();
    for (int i = tid; i < 2 * NBIN; i += 256) hist[i] = base[i];
    __syncthreads();
    for (int i = tid; i < n; i += 256) {
        int u = ei[e0 + i], p = ei[Ee + e0 + i];
        int bp = p >> BSH, bu = u >> BSH;
        int rp = atomicAdd(&hist[bp], 1);
        if (rp < BCAP)
            ent_p[(size_t)bp * BCAP + rp] = ((uint_t)(p & (BINSZ - 1)) << 16) | (uint_t)u;
        int ru = atomicAdd(&hist[NBIN + bu], 1);
        if (ru < BCAP)
            ent_u[(size_t)bu * BCAP + ru] = ((uint_t)(u & (BINSZ - 1)) << 16) | (uint_t)p;
    }
}

// ---------------- per-bin scatter with inline bin-base scan ----------------
__global__ __launch_bounds__(512) void k_scatter(
    const uint_t* __restrict__ ent_p, const uint_t* __restrict__ ent_u,
    const int* __restrict__ bin_cnt,
    int* __restrict__ off, int* __restrict__ cnt,
    int* __restrict__ src_p, int* __restrict__ src_u) {
    __shared__ int ca[BINSZ];
    __shared__ int cb[BINSZ];
    __shared__ int bb[128];
    int side = blockIdx.y, b = blockIdx.x, t = threadIdx.x;
    const uint_t* E = (side ? ent_u : ent_p) + (size_t)b * BCAP;
    int* src = side ? src_u : src_p;

    // inline exclusive prefix over the 98 bins of this side
    if (t < 128) {
        int v = 0;
        if (t < NBIN) { v = bin_cnt[side * NBIN + t]; if (v > BCAP) v = BCAP; }
        bb[t] = v;
    }
    __syncthreads();
    #pragma unroll
    for (int d = 1; d < 128; d <<= 1) {
        int x = 0;
        if (t < 128 && t >= d) x = bb[t - d];
        __syncthreads();
        if (t < 128) bb[t] += x;
        __syncthreads();
    }
    int nb = bin_cnt[side * NBIN + b]; if (nb > BCAP) nb = BCAP;
    int base = bb[b] - nb;   // exclusive prefix

    ca[t] = 0;
    __syncthreads();
    for (int i = t; i < nb; i += 512)
        atomicAdd(&ca[E[i] >> 16], 1);
    __syncthreads();
    int v = ca[t];
    int* A = ca; int* B = cb;
    #pragma unroll
    for (int d = 1; d < BINSZ; d <<= 1) {
        int x = A[t] + ((t >= d) ? A[t - d] : 0);
        B[t] = x;
        __syncthreads();
        int* tmp = A; A = B; B = tmp;
    }
    int excl = A[t] - v;
    B[t] = excl;
    __syncthreads();
    for (int i = t; i < nb; i += 512) {
        uint_t e = E[i];
        int sl = atomicAdd(&B[e >> 16], 1);
        src[base + sl] = (int)(e & 0xffffu);
    }
    int d = (b << BSH) + t;
    if (d < Nn) {
        off[side * Nn + d] = base + excl;
        cnt[side * Nn + d] = v;
    }
}

// ---------------- layer-1 mean aggregation: 8 lanes x uint4 per fp8 row ----------------
// lane l of the 8-lane group owns dims l*16..l*16+15 (16 f32 acc); one VMEM per row.
__global__ __launch_bounds__(256) void k_agg1(
    const uint4* __restrict__ xu8, const uint4* __restrict__ xp8,
    const int* __restrict__ off, const int* __restrict__ cnt,
    const int* __restrict__ src_p, const int* __restrict__ src_u,
    us_t* __restrict__ cu, us_t* __restrict__ cp) {
    int side = blockIdx.y;
    const uint4* X = side ? xp8 : xu8;
    const int* of = off + side * Nn;
    const int* cn = cnt + side * Nn;
    const int* sr = side ? src_u : src_p;
    us_t* out = side ? cp : cu;

    int node = blockIdx.x * 32 + (threadIdx.x >> 3);
    if (node >= Nn) return;
    int l = threadIdx.x & 7;
    int s = of[node], c = cn[node];
    float ac[16];
    #pragma unroll
    for (int i = 0; i < 16; ++i) ac[i] = 0.f;

    int j = 0;
    for (; j + 8 <= c; j += 8) {
        int ss[8];
        #pragma unroll
        for (int q = 0; q < 8; ++q) ss[q] = sr[s + j + q];
        uint4 vv[8];
        #pragma unroll
        for (int q = 0; q < 8; ++q) vv[q] = X[(size_t)ss[q] * 8 + l];
        #pragma unroll
        for (int q = 0; q < 8; ++q) {
            const uint_t* pw = reinterpret_cast<const uint_t*>(&vv[q]);
            #pragma unroll
            for (int h = 0; h < 4; ++h) {
                f32x2 plo = __builtin_amdgcn_cvt_pk_f32_fp8((int)pw[h], false);
                f32x2 phi = __builtin_amdgcn_cvt_pk_f32_fp8((int)pw[h], true);
                ac[h * 4 + 0] += plo[0]; ac[h * 4 + 1] += plo[1];
                ac[h * 4 + 2] += phi[0]; ac[h * 4 + 3] += phi[1];
            }
        }
    }
    for (; j < c; ++j) {
        uint4 v0 = X[(size_t)sr[s + j] * 8 + l];
        const uint_t* pw = reinterpret_cast<const uint_t*>(&v0);
        #pragma unroll
        for (int h = 0; h < 4; ++h) {
            f32x2 plo = __builtin_amdgcn_cvt_pk_f32_fp8((int)pw[h], false);
            f32x2 phi = __builtin_amdgcn_cvt_pk_f32_fp8((int)pw[h], true);
            ac[h * 4 + 0] += plo[0]; ac[h * 4 + 1] += plo[1];
            ac[h * 4 + 2] += phi[0]; ac[h * 4 + 3] += phi[1];
        }
    }
    float inv = 1.0f / fmaxf((float)c, 1.0f);
    uint_t ow[8];
    #pragma unroll
    for (int i = 0; i < 8; ++i)
        ow[i] = (uint_t)f2bf(ac[2 * i] * inv) | ((uint_t)f2bf(ac[2 * i + 1] * inv) << 16);
    uint4* dst = reinterpret_cast<uint4*>(out + (size_t)node * 256 + l * 16);
    uint4 o0 = {ow[0], ow[1], ow[2], ow[3]};
    uint4 o1 = {ow[4], ow[5], ow[6], ow[7]};
    dst[0] = o0;
    dst[1] = o1;
}

// ---------------- layer-2 mean aggregation: 8 lanes x uint4 per bf16 row ----------------
// lane l owns dims l*8..l*8+7; adds into f32 out.
__global__ __launch_bounds__(256) void k_agg2(
    const uint4* __restrict__ tu, const uint4* __restrict__ tp,
    const int* __restrict__ off, const int* __restrict__ cnt,
    const int* __restrict__ src_p, const int* __restrict__ src_u,
    float* __restrict__ ou, float* __restrict__ op) {
    int side = blockIdx.y;
    const uint4* T = side ? tp : tu;
    const int* of = off + side * Nn;
    const int* cn = cnt + side * Nn;
    const int* sr = side ? src_u : src_p;
    float* out = side ? op : ou;

    int node = blockIdx.x * 32 + (threadIdx.x >> 3);
    if (node >= Nn) return;
    int l = threadIdx.x & 7;
    int s = of[node], c = cn[node];
    float ac[8];
    #pragma unroll
    for (int i = 0; i < 8; ++i) ac[i] = 0.f;

    int j = 0;
    for (; j + 8 <= c; j += 8) {
        int ss[8];
        #pragma unroll
        for (int q = 0; q < 8; ++q) ss[q] = sr[s + j + q];
        uint4 vv[8];
        #pragma unroll
        for (int q = 0; q < 8; ++q) vv[q] = T[(size_t)ss[q] * 8 + l];
        #pragma unroll
        for (int q = 0; q < 8; ++q) {
            const uint_t* pw = reinterpret_cast<const uint_t*>(&vv[q]);
            #pragma unroll
            for (int h = 0; h < 4; ++h) {
                ac[h * 2 + 0] += bflo(pw[h]);
                ac[h * 2 + 1] += bfhi(pw[h]);
            }
        }
    }
    for (; j < c; ++j) {
        uint4 v0 = T[(size_t)sr[s + j] * 8 + l];
        const uint_t* pw = reinterpret_cast<const uint_t*>(&v0);
        #pragma unroll
        for (int h = 0; h < 4; ++h) {
            ac[h * 2 + 0] += bflo(pw[h]);
            ac[h * 2 + 1] += bfhi(pw[h]);
        }
    }
    float inv = 1.0f / fmaxf((float)c, 1.0f);
    float4* po = reinterpret_cast<float4*>(out + (size_t)node * 64) + l * 2;
    float4 p0 = po[0], p1 = po[1];
    p0.x += ac[0] * inv; p0.y += ac[1] * inv; p0.z += ac[2] * inv; p0.w += ac[3] * inv;
    p1.x += ac[4] * inv; p1.y += ac[5] * inv; p1.z += ac[6] * inv; p1.w += ac[7] * inv;
    po[0] = p0; po[1] = p1;
}

// ---------------- A-tile stage: 64 rows x 256 K bf16 = 32 KB, XOR-swizzled ----------------
#define STAGE_A(Ag, mt, b)                                                          \
    {                                                                               \
        int base_ = (mt) * 64;                                                      \
        _Pragma("unroll")                                                           \
        for (int ii = 0; ii < 4; ++ii) {                                            \
            int s_ = ii * 512 + tid;                                                \
            int row_ = s_ >> 5, ks_ = s_ & 31;                                      \
            int ksl_ = ks_ ^ (row_ & 7);                                            \
            int gr_ = base_ + row_; if (gr_ >= Nn) gr_ = Nn - 1;                    \
            GLOAD((Ag) + (size_t)gr_ * 256 + ksl_ * 8, &sA[b][(s_ - lane) * 8]);    \
        }                                                                           \
    }

// ---------------- layer-1 GEMM: M=50000, K=256, N=256; W in registers ----------------
__global__ __launch_bounds__(512) void k_mm1(
    const us_t* __restrict__ cu, const us_t* __restrict__ cp,
    const us_t* __restrict__ wc10, const us_t* __restrict__ wc11,
    const float* __restrict__ bu1, const float* __restrict__ bp1,
    us_t* __restrict__ hu, us_t* __restrict__ hp) {
    __shared__ us_t sA[2][64 * 256];
    int tid = threadIdx.x, lane = tid & 63;
    int wv = tid >> 6, wr = wv >> 2, wc = wv & 3;
    int job = blockIdx.y;
    const us_t* Ag = job ? cp : cu;
    const us_t* W = job ? wc11 : wc10;
    const float* bias = job ? bp1 : bu1;
    us_t* C = job ? hp : hu;

    short8 wf[4][8];
    #pragma unroll
    for (int n = 0; n < 4; ++n)
        #pragma unroll
        for (int ks = 0; ks < 8; ++ks) {
            int col = wc * 64 + n * 16 + (lane & 15);
            wf[n][ks] = *reinterpret_cast<const short8*>(
                W + (size_t)col * 256 + ks * 32 + (lane >> 4) * 8);
        }
    float bv[4];
    #pragma unroll
    for (int n = 0; n < 4; ++n) bv[n] = bias[wc * 64 + n * 16 + (lane & 15)];

    int bx = blockIdx.x;
    int NT = (MT_TOT - 1 - bx) / GX + 1;
    STAGE_A(Ag, bx, 0);
    for (int t = 0; t < NT; ++t) {
        int mt = bx + t * GX;
        if (t + 1 < NT) {
            STAGE_A(Ag, bx + (t + 1) * GX, (t + 1) & 1);
            asm volatile("s_waitcnt vmcnt(4)" ::: "memory");
        } else {
            asm volatile("s_waitcnt vmcnt(0)" ::: "memory");
        }
        __syncthreads();
        const us_t* sAc = sA[t & 1];

        f32x4 acc[2][4];
        #pragma unroll
        for (int m = 0; m < 2; ++m)
            #pragma unroll
            for (int n = 0; n < 4; ++n)
                #pragma unroll
                for (int i = 0; i < 4; ++i) acc[m][n][i] = 0.f;

        #pragma unroll
        for (int ks = 0; ks < 8; ++ks) {
            short8 af[2];
            #pragma unroll
            for (int m = 0; m < 2; ++m) {
                int row = wr * 32 + m * 16 + (lane & 15);
                int sl = (ks * 4 + (lane >> 4)) ^ (row & 7);
                af[m] = *reinterpret_cast<const short8*>(&sAc[row * 256 + sl * 8]);
            }
            #pragma unroll
            for (int m = 0; m < 2; ++m)
                #pragma unroll
                for (int n = 0; n < 4; ++n)
                    acc[m][n] = __builtin_amdgcn_mfma_f32_16x16x32_bf16(
                        af[m], wf[n][ks], acc[m][n], 0, 0, 0);
        }

        int mbase = mt * 64;
        #pragma unroll
        for (int n = 0; n < 4; ++n) {
            int col = wc * 64 + n * 16 + (lane & 15);
            #pragma unroll
            for (int m = 0; m < 2; ++m) {
                int row0 = mbase + wr * 32 + m * 16 + ((lane >> 4) << 2);
                #pragma unroll
                for (int j = 0; j < 4; ++j) {
                    int row = row0 + j;
                    if (row < Nn)
                        C[(size_t)row * HIDD + col] =
                            f2bf(fmaxf(acc[m][n][j] + bv[n], 0.f));
                }
            }
        }
        __syncthreads();
    }
}

// ---------------- layer-2 GEMM: M=50000, K=256, N=128; W in registers ----------------
__global__ __launch_bounds__(512) void k_mm2(
    const us_t* __restrict__ hu, const us_t* __restrict__ hp,
    const us_t* __restrict__ wc20, const us_t* __restrict__ wc21,
    const float* __restrict__ bu2, const float* __restrict__ bp2,
    us_t* __restrict__ tu, us_t* __restrict__ tp,
    float* __restrict__ ou, float* __restrict__ op) {
    __shared__ us_t sA[2][64 * 256];
    int tid = threadIdx.x, lane = tid & 63;
    int wv = tid >> 6, wr = wv >> 2, wc = wv & 3;
    int job = blockIdx.y;
    const us_t* Ag = job ? hp : hu;
    const us_t* W = job ? wc21 : wc20;
    const float* bias = job ? bu2 : bp2;
    us_t* T = job ? tp : tu;
    float* O = job ? ou : op;

    short8 wf[2][8];
    #pragma unroll
    for (int n = 0; n < 2; ++n)
        #pragma unroll
        for (int ks = 0; ks < 8; ++ks) {
            int col = wc * 32 + n * 16 + (lane & 15);
            wf[n][ks] = *reinterpret_cast<const short8*>(
                W + (size_t)col * 256 + ks * 32 + (lane >> 4) * 8);
        }
    float bv[2];
    #pragma unroll
    for (int n = 0; n < 2; ++n) {
        int col = wc * 32 + n * 16 + (lane & 15);
        bv[n] = (col >= 64) ? bias[col - 64] : 0.f;
    }

    int bx = blockIdx.x;
    int NT = (MT_TOT - 1 - bx) / GX + 1;
    STAGE_A(Ag, bx, 0);
    for (int t = 0; t < NT; ++t) {
        int mt = bx + t * GX;
        if (t + 1 < NT) {
            STAGE_A(Ag, bx + (t + 1) * GX, (t + 1) & 1);
            asm volatile("s_waitcnt vmcnt(4)" ::: "memory");
        } else {
            asm volatile("s_waitcnt vmcnt(0)" ::: "memory");
        }
        __syncthreads();
        const us_t* sAc = sA[t & 1];

        f32x4 acc[2][2];
        #pragma unroll
        for (int m = 0; m < 2; ++m)
            #pragma unroll
            for (int n = 0; n < 2; ++n)
                #pragma unroll
                for (int i = 0; i < 4; ++i) acc[m][n][i] = 0.f;

        #pragma unroll
        for (int ks = 0; ks < 8; ++ks) {
            short8 af[2];
            #pragma unroll
            for (int m = 0; m < 2; ++m) {
                int row = wr * 32 + m * 16 + (lane & 15);
                int sl = (ks * 4 + (lane >> 4)) ^ (row & 7);
                af[m] = *reinterpret_cast<const short8*>(&sAc[row * 256 + sl * 8]);
            }
            #pragma unroll
            for (int m = 0; m < 2; ++m)
                #pragma unroll
                for (int n = 0; n < 2; ++n)
                    acc[m][n] = __builtin_amdgcn_mfma_f32_16x16x32_bf16(
                        af[m], wf[n][ks], acc[m][n], 0, 0, 0);
        }

        int mbase = mt * 64;
        #pragma unroll
        for (int n = 0; n < 2; ++n) {
            int col = wc * 32 + n * 16 + (lane & 15);
            bool top = col < 64;
            int cc = top ? col : col - 64;
            #pragma unroll
            for (int m = 0; m < 2; ++m) {
                int row0 = mbase + wr * 32 + m * 16 + ((lane >> 4) << 2);
                #pragma unroll
                for (int j = 0; j < 4; ++j) {
                    int row = row0 + j;
                    if (row >= Nn) continue;
                    float v = acc[m][n][j] + bv[n];
                    if (top) T[(size_t)row * 64 + cc] = f2bf(v);
                    else     O[(size_t)row * 64 + cc] = v;
                }
            }
        }
        __syncthreads();
    }
}

// ---------------- launch ----------------
extern "C" void kernel_launch(void* const* d_in, const int* in_sizes, int n_in,
                              void* d_out, int out_size, void* d_ws, size_t ws_size,
                              hipStream_t stream) {
    const float* x_user    = (const float*)d_in[0];
    const float* x_product = (const float*)d_in[1];
    const int*   ei        = (const int*)d_in[2];
    const float* w_u1_l = (const float*)d_in[3];
    const float* b_u1   = (const float*)d_in[4];
    const float* w_u1_r = (const float*)d_in[5];
    const float* w_p1_l = (const float*)d_in[6];
    const float* b_p1   = (const float*)d_in[7];
    const float* w_p1_r = (const float*)d_in[8];
    const float* w_u2_l = (const float*)d_in[9];
    const float* b_u2   = (const float*)d_in[10];
    const float* w_u2_r = (const float*)d_in[11];
    const float* w_p2_l = (const float*)d_in[12];
    const float* b_p2   = (const float*)d_in[13];
    const float* w_p2_r = (const float*)d_in[14];

    float* out_u = (float*)d_out;
    float* out_p = out_u + (size_t)Nn * CLSS;

    char* w = (char*)d_ws;
    int* bin_cnt  = (int*)w; w += (size_t)2 * NBIN * 4;
    int* off  = (int*)w;  w += (size_t)2 * Nn * 4;
    int* cnt  = (int*)w;  w += (size_t)2 * Nn * 4;
    int* src_p = (int*)w; w += (size_t)Ee * 4;
    int* src_u = (int*)w; w += (size_t)Ee * 4;
    uint_t* ent_p = (uint_t*)w; w += (size_t)NBIN * BCAP * 4;
    uint_t* ent_u = (uint_t*)w; w += (size_t)NBIN * BCAP * 4;
    uintptr_t a = (uintptr_t)w; a = (a + 255) & ~(uintptr_t)255; w = (char*)a;
    us_t* cu   = (us_t*)w; w += (size_t)Nn * 256 * 2;   // [mean_u | x_prod]
    us_t* cp   = (us_t*)w; w += (size_t)Nn * 256 * 2;   // [mean_p | x_user]
    uint_t* xf8u = (uint_t*)w; w += (size_t)Nn * FIN;
    uint_t* xf8p = (uint_t*)w; w += (size_t)Nn * FIN;
    us_t* h_u  = (us_t*)w; w += (size_t)Nn * HIDD * 2;
    us_t* h_p  = (us_t*)w; w += (size_t)Nn * HIDD * 2;
    us_t* tbuf_u = (us_t*)w; w += (size_t)Nn * CLSS * 2;
    us_t* tbuf_p = (us_t*)w; w += (size_t)Nn * CLSS * 2;
    us_t* wc10 = (us_t*)w; w += (size_t)256 * 256 * 2;
    us_t* wc11 = (us_t*)w; w += (size_t)256 * 256 * 2;
    us_t* wc20 = (us_t*)w; w += (size_t)128 * 256 * 2;
    us_t* wc21 = (us_t*)w; w += (size_t)128 * 256 * 2;

    // conversions + bin_cnt zero
    {
        int n4 = (Nn * FIN) / 4;
        int blocks = (n4 + 255) / 256; if (blocks > 1024) blocks = 1024;
        dim3 g(blocks, 2);
        k_cvtx<<<g, 256, 0, stream>>>(x_user, x_product, cu, cp, xf8u, xf8p, n4);
    }
    k_cvtw<<<193, 256, 0, stream>>>(w_u1_l, w_u1_r, w_p1_l, w_p1_r,
                                    w_u2_l, w_u2_r, w_p2_l, w_p2_r,
                                    wc10, wc11, wc20, wc21, bin_cnt);

    // binned CSR build
    k_bin<<<NEB, 256, 0, stream>>>(ei, bin_cnt, ent_p, ent_u);
    dim3 gsc(NBIN, 2);
    k_scatter<<<gsc, 512, 0, stream>>>(ent_p, ent_u, bin_cnt,
                                       off, cnt, src_p, src_u);

    // ---- layer 1 ----
    dim3 ga1((Nn + 31) / 32, 2);
    k_agg1<<<ga1, 256, 0, stream>>>((const uint4*)xf8u, (const uint4*)xf8p,
                                    off, cnt, src_p, src_u, cu, cp);
    dim3 g1(GX, 2);
    k_mm1<<<g1, 512, 0, stream>>>(cu, cp, wc10, wc11, b_u1, b_p1, h_u, h_p);

    // ---- layer 2 ----
    dim3 g2(GX, 2);
    k_mm2<<<g2, 512, 0, stream>>>(h_u, h_p, wc20, wc21, b_u2, b_p2,
                                  tbuf_u, tbuf_p, out_u, out_p);
    dim3 ga2((Nn + 31) / 32, 2);
    k_agg2<<<ga2, 256, 0, stream>>>((const uint4*)tbuf_u, (const uint4*)tbuf_p,
                                    off, cnt, src_p, src_u, out_u, out_p);
}

// Round 11
// 182.990 us; speedup vs baseline: 1.2207x; 1.0242x over previous
//
#include <hip/hip_runtime.h>
#include <stdint.h>

#define Nn 50000
#define Ee 800000
#define FIN 128
#define HIDD 256
#define CLSS 64

#define NBIN 98          // ceil(50000 / 512)
#define BSH 9
#define BINSZ 512
#define BCAP 16384
#define EPB 2048
#define NEB ((Ee + EPB - 1) / EPB)   // 391

#define MT_TOT 782       // ceil(50000/64)
#define GX 112           // M-group blocks per job

typedef unsigned int uint_t;
typedef unsigned short us_t;
typedef __attribute__((ext_vector_type(8))) short short8;
typedef __attribute__((ext_vector_type(4))) float f32x4;
typedef __attribute__((ext_vector_type(2))) float f32x2;

__device__ inline float bflo(uint_t v) { union { uint_t u; float f; } c; c.u = v << 16; return c.f; }
__device__ inline float bfhi(uint_t v) { union { uint_t u; float f; } c; c.u = v & 0xffff0000u; return c.f; }
__device__ inline us_t f2bf(float f) {
    union { float f; uint_t u; } c; c.f = f;
    uint_t u = c.u;
    u += 0x7fffu + ((u >> 16) & 1u);
    return (us_t)(u >> 16);
}

#define GLOAD(gp, lp)                                                      \
    __builtin_amdgcn_global_load_lds(                                      \
        (const __attribute__((address_space(1))) unsigned int*)(gp),       \
        (__attribute__((address_space(3))) unsigned int*)(lp), 16, 0, 0)

// ================= merged front-end: k_bin || cvtw || cvtx =================
// blocks [0, NEB)            : edge binning (needs bin_cnt pre-zeroed)
// blocks [NEB, NEB+96)       : weight convert (49152 elems, 512/block)
// blocks [NEB+96, NEB+96+512): x convert f32 -> bf16 comb-backhalf + fp8 table
__global__ __launch_bounds__(512) void k_front(
    const int* __restrict__ ei,
    const float* __restrict__ xu, const float* __restrict__ xp,
    const float* __restrict__ w1, const float* __restrict__ w2,
    const float* __restrict__ w3, const float* __restrict__ w4,
    const float* __restrict__ w5, const float* __restrict__ w6,
    const float* __restrict__ w7, const float* __restrict__ w8,
    us_t* __restrict__ cu, us_t* __restrict__ cp,
    uint_t* __restrict__ f8u, uint_t* __restrict__ f8p,
    us_t* __restrict__ wc10, us_t* __restrict__ wc11,
    us_t* __restrict__ wc20, us_t* __restrict__ wc21,
    int* __restrict__ bin_cnt,
    uint_t* __restrict__ ent_p, uint_t* __restrict__ ent_u) {
    __shared__ int hist[2 * NBIN];
    __shared__ int base[2 * NBIN];
    int bx = blockIdx.x, tid = threadIdx.x;

    if (bx < NEB) {
        // ---- edge binning ----
        int e0 = bx * EPB;
        int n = Ee - e0; if (n > EPB) n = EPB;
        for (int i = tid; i < 2 * NBIN; i += 512) hist[i] = 0;
        __syncthreads();
        for (int i = tid; i < n; i += 512) {
            int u = ei[e0 + i], p = ei[Ee + e0 + i];
            atomicAdd(&hist[p >> BSH], 1);
            atomicAdd(&hist[NBIN + (u >> BSH)], 1);
        }
        __syncthreads();
        for (int i = tid; i < 2 * NBIN; i += 512) {
            int c = hist[i];
            base[i] = c ? atomicAdd(&bin_cnt[i], c) : 0;
        }
        __syncthreads();
        for (int i = tid; i < 2 * NBIN; i += 512) hist[i] = base[i];
        __syncthreads();
        for (int i = tid; i < n; i += 512) {
            int u = ei[e0 + i], p = ei[Ee + e0 + i];
            int bp = p >> BSH, bu = u >> BSH;
            int rp = atomicAdd(&hist[bp], 1);
            if (rp < BCAP)
                ent_p[(size_t)bp * BCAP + rp] = ((uint_t)(p & (BINSZ - 1)) << 16) | (uint_t)u;
            int ru = atomicAdd(&hist[NBIN + bu], 1);
            if (ru < BCAP)
                ent_u[(size_t)bu * BCAP + ru] = ((uint_t)(u & (BINSZ - 1)) << 16) | (uint_t)p;
        }
    } else if (bx < NEB + 96) {
        // ---- weight convert ----
        int i = (bx - NEB) * 512 + tid;    // 0..49151
        const float* wp; us_t* dst;
        if (i < 32768) {
            int seg = i >> 13; int loc = i & 8191;
            int row = loc >> 5, col = (loc & 31) * 4;
            switch (seg) {
                case 0: wp = w1; dst = wc10 + (size_t)row * 256 + col; break;
                case 1: wp = w2; dst = wc10 + (size_t)row * 256 + 128 + col; break;
                case 2: wp = w3; dst = wc11 + (size_t)row * 256 + col; break;
                default: wp = w4; dst = wc11 + (size_t)row * 256 + 128 + col; break;
            }
            float4 v = reinterpret_cast<const float4*>(wp)[i & 8191];
            ushort4 o;
            o.x = f2bf(v.x); o.y = f2bf(v.y); o.z = f2bf(v.z); o.w = f2bf(v.w);
            *reinterpret_cast<ushort4*>(dst) = o;
        } else {
            int j = i - 32768;
            int seg = j >> 12; int loc = j & 4095;
            switch (seg) {
                case 0: wp = w5; dst = wc20; break;
                case 1: wp = w6; dst = wc21 + 64 * 256; break;
                case 2: wp = w7; dst = wc21; break;
                default: wp = w8; dst = wc20 + 64 * 256; break;
            }
            float4 v = reinterpret_cast<const float4*>(wp)[loc];
            ushort4 o;
            o.x = f2bf(v.x); o.y = f2bf(v.y); o.z = f2bf(v.z); o.w = f2bf(v.w);
            reinterpret_cast<ushort4*>(dst)[loc] = o;
        }
    } else {
        // ---- x convert ----
        int bcx = bx - NEB - 96;           // 0..511
        int side = bcx & 1;
        const float* in = side ? xp : xu;
        us_t* comb = side ? cu : cp;       // x_prod -> cu backhalf, x_user -> cp backhalf
        uint_t* o8 = side ? f8p : f8u;
        const int n4 = (Nn * FIN) / 4;     // 1.6M
        int i = (bcx >> 1) * 512 + tid;
        int stride = 256 * 512;
        for (; i < n4; i += stride) {
            float4 v = reinterpret_cast<const float4*>(in)[i];
            ushort4 o;
            o.x = f2bf(v.x); o.y = f2bf(v.y); o.z = f2bf(v.z); o.w = f2bf(v.w);
            int node = i >> 5;
            int col = (i & 31) * 4;
            *reinterpret_cast<ushort4*>(comb + (size_t)node * 256 + 128 + col) = o;
            int pk = __builtin_amdgcn_cvt_pk_fp8_f32(v.x, v.y, 0, false);
            pk = __builtin_amdgcn_cvt_pk_fp8_f32(v.z, v.w, pk, true);
            o8[i] = (uint_t)pk;
        }
    }
}

// ---------------- per-bin scatter with inline bin-base scan ----------------
__global__ __launch_bounds__(512) void k_scatter(
    const uint_t* __restrict__ ent_p, const uint_t* __restrict__ ent_u,
    const int* __restrict__ bin_cnt,
    int* __restrict__ off, int* __restrict__ cnt,
    int* __restrict__ src_p, int* __restrict__ src_u) {
    __shared__ int ca[BINSZ];
    __shared__ int cb[BINSZ];
    __shared__ int bb[128];
    int side = blockIdx.y, b = blockIdx.x, t = threadIdx.x;
    const uint_t* E = (side ? ent_u : ent_p) + (size_t)b * BCAP;
    int* src = side ? src_u : src_p;

    if (t < 128) {
        int v = 0;
        if (t < NBIN) { v = bin_cnt[side * NBIN + t]; if (v > BCAP) v = BCAP; }
        bb[t] = v;
    }
    __syncthreads();
    #pragma unroll
    for (int d = 1; d < 128; d <<= 1) {
        int x = 0;
        if (t < 128 && t >= d) x = bb[t - d];
        __syncthreads();
        if (t < 128) bb[t] += x;
        __syncthreads();
    }
    int nb = bin_cnt[side * NBIN + b]; if (nb > BCAP) nb = BCAP;
    int base = bb[b] - nb;

    ca[t] = 0;
    __syncthreads();
    for (int i = t; i < nb; i += 512)
        atomicAdd(&ca[E[i] >> 16], 1);
    __syncthreads();
    int v = ca[t];
    int* A = ca; int* B = cb;
    #pragma unroll
    for (int d = 1; d < BINSZ; d <<= 1) {
        int x = A[t] + ((t >= d) ? A[t - d] : 0);
        B[t] = x;
        __syncthreads();
        int* tmp = A; A = B; B = tmp;
    }
    int excl = A[t] - v;
    B[t] = excl;
    __syncthreads();
    for (int i = t; i < nb; i += 512) {
        uint_t e = E[i];
        int sl = atomicAdd(&B[e >> 16], 1);
        src[base + sl] = (int)(e & 0xffffu);
    }
    int d = (b << BSH) + t;
    if (d < Nn) {
        off[side * Nn + d] = base + excl;
        cnt[side * Nn + d] = v;
    }
}

// ---------------- layer-1 mean aggregation: 8 lanes x uint4 per fp8 row ----------------
__global__ __launch_bounds__(256) void k_agg1(
    const uint4* __restrict__ xu8, const uint4* __restrict__ xp8,
    const int* __restrict__ off, const int* __restrict__ cnt,
    const int* __restrict__ src_p, const int* __restrict__ src_u,
    us_t* __restrict__ cu, us_t* __restrict__ cp) {
    int side = blockIdx.y;
    const uint4* X = side ? xp8 : xu8;
    const int* of = off + side * Nn;
    const int* cn = cnt + side * Nn;
    const int* sr = side ? src_u : src_p;
    us_t* out = side ? cp : cu;

    int node = blockIdx.x * 32 + (threadIdx.x >> 3);
    if (node >= Nn) return;
    int l = threadIdx.x & 7;
    int s = of[node], c = cn[node];
    float ac[16];
    #pragma unroll
    for (int i = 0; i < 16; ++i) ac[i] = 0.f;

    int j = 0;
    for (; j + 8 <= c; j += 8) {
        int ss[8];
        #pragma unroll
        for (int q = 0; q < 8; ++q) ss[q] = sr[s + j + q];
        uint4 vv[8];
        #pragma unroll
        for (int q = 0; q < 8; ++q) vv[q] = X[(size_t)ss[q] * 8 + l];
        #pragma unroll
        for (int q = 0; q < 8; ++q) {
            const uint_t* pw = reinterpret_cast<const uint_t*>(&vv[q]);
            #pragma unroll
            for (int h = 0; h < 4; ++h) {
                f32x2 plo = __builtin_amdgcn_cvt_pk_f32_fp8((int)pw[h], false);
                f32x2 phi = __builtin_amdgcn_cvt_pk_f32_fp8((int)pw[h], true);
                ac[h * 4 + 0] += plo[0]; ac[h * 4 + 1] += plo[1];
                ac[h * 4 + 2] += phi[0]; ac[h * 4 + 3] += phi[1];
            }
        }
    }
    for (; j < c; ++j) {
        uint4 v0 = X[(size_t)sr[s + j] * 8 + l];
        const uint_t* pw = reinterpret_cast<const uint_t*>(&v0);
        #pragma unroll
        for (int h = 0; h < 4; ++h) {
            f32x2 plo = __builtin_amdgcn_cvt_pk_f32_fp8((int)pw[h], false);
            f32x2 phi = __builtin_amdgcn_cvt_pk_f32_fp8((int)pw[h], true);
            ac[h * 4 + 0] += plo[0]; ac[h * 4 + 1] += plo[1];
            ac[h * 4 + 2] += phi[0]; ac[h * 4 + 3] += phi[1];
        }
    }
    float inv = 1.0f / fmaxf((float)c, 1.0f);
    uint_t ow[8];
    #pragma unroll
    for (int i = 0; i < 8; ++i)
        ow[i] = (uint_t)f2bf(ac[2 * i] * inv) | ((uint_t)f2bf(ac[2 * i + 1] * inv) << 16);
    uint4* dst = reinterpret_cast<uint4*>(out + (size_t)node * 256 + l * 16);
    uint4 o0 = {ow[0], ow[1], ow[2], ow[3]};
    uint4 o1 = {ow[4], ow[5], ow[6], ow[7]};
    dst[0] = o0;
    dst[1] = o1;
}

// ---------------- layer-2 mean aggregation: 8 lanes x uint4 per bf16 row ----------------
__global__ __launch_bounds__(256) void k_agg2(
    const uint4* __restrict__ tu, const uint4* __restrict__ tp,
    const int* __restrict__ off, const int* __restrict__ cnt,
    const int* __restrict__ src_p, const int* __restrict__ src_u,
    float* __restrict__ ou, float* __restrict__ op) {
    int side = blockIdx.y;
    const uint4* T = side ? tp : tu;
    const int* of = off + side * Nn;
    const int* cn = cnt + side * Nn;
    const int* sr = side ? src_u : src_p;
    float* out = side ? op : ou;

    int node = blockIdx.x * 32 + (threadIdx.x >> 3);
    if (node >= Nn) return;
    int l = threadIdx.x & 7;
    int s = of[node], c = cn[node];
    float ac[8];
    #pragma unroll
    for (int i = 0; i < 8; ++i) ac[i] = 0.f;

    int j = 0;
    for (; j + 8 <= c; j += 8) {
        int ss[8];
        #pragma unroll
        for (int q = 0; q < 8; ++q) ss[q] = sr[s + j + q];
        uint4 vv[8];
        #pragma unroll
        for (int q = 0; q < 8; ++q) vv[q] = T[(size_t)ss[q] * 8 + l];
        #pragma unroll
        for (int q = 0; q < 8; ++q) {
            const uint_t* pw = reinterpret_cast<const uint_t*>(&vv[q]);
            #pragma unroll
            for (int h = 0; h < 4; ++h) {
                ac[h * 2 + 0] += bflo(pw[h]);
                ac[h * 2 + 1] += bfhi(pw[h]);
            }
        }
    }
    for (; j < c; ++j) {
        uint4 v0 = T[(size_t)sr[s + j] * 8 + l];
        const uint_t* pw = reinterpret_cast<const uint_t*>(&v0);
        #pragma unroll
        for (int h = 0; h < 4; ++h) {
            ac[h * 2 + 0] += bflo(pw[h]);
            ac[h * 2 + 1] += bfhi(pw[h]);
        }
    }
    float inv = 1.0f / fmaxf((float)c, 1.0f);
    float4* po = reinterpret_cast<float4*>(out + (size_t)node * 64) + l * 2;
    float4 p0 = po[0], p1 = po[1];
    p0.x += ac[0] * inv; p0.y += ac[1] * inv; p0.z += ac[2] * inv; p0.w += ac[3] * inv;
    p1.x += ac[4] * inv; p1.y += ac[5] * inv; p1.z += ac[6] * inv; p1.w += ac[7] * inv;
    po[0] = p0; po[1] = p1;
}

// ---------------- A-tile stage: 64 rows x 256 K bf16 = 32 KB, XOR-swizzled ----------------
#define STAGE_A(Ag, mt, b)                                                          \
    {                                                                               \
        int base_ = (mt) * 64;                                                      \
        _Pragma("unroll")                                                           \
        for (int ii = 0; ii < 4; ++ii) {                                            \
            int s_ = ii * 512 + tid;                                                \
            int row_ = s_ >> 5, ks_ = s_ & 31;                                      \
            int ksl_ = ks_ ^ (row_ & 7);                                            \
            int gr_ = base_ + row_; if (gr_ >= Nn) gr_ = Nn - 1;                    \
            GLOAD((Ag) + (size_t)gr_ * 256 + ksl_ * 8, &sA[b][(s_ - lane) * 8]);    \
        }                                                                           \
    }

// ---------------- layer-1 GEMM: M=50000, K=256, N=256; W in registers ----------------
__global__ __launch_bounds__(512) void k_mm1(
    const us_t* __restrict__ cu, const us_t* __restrict__ cp,
    const us_t* __restrict__ wc10, const us_t* __restrict__ wc11,
    const float* __restrict__ bu1, const float* __restrict__ bp1,
    us_t* __restrict__ hu, us_t* __restrict__ hp) {
    __shared__ us_t sA[2][64 * 256];
    int tid = threadIdx.x, lane = tid & 63;
    int wv = tid >> 6, wr = wv >> 2, wc = wv & 3;
    int job = blockIdx.y;
    const us_t* Ag = job ? cp : cu;
    const us_t* W = job ? wc11 : wc10;
    const float* bias = job ? bp1 : bu1;
    us_t* C = job ? hp : hu;

    short8 wf[4][8];
    #pragma unroll
    for (int n = 0; n < 4; ++n)
        #pragma unroll
        for (int ks = 0; ks < 8; ++ks) {
            int col = wc * 64 + n * 16 + (lane & 15);
            wf[n][ks] = *reinterpret_cast<const short8*>(
                W + (size_t)col * 256 + ks * 32 + (lane >> 4) * 8);
        }
    float bv[4];
    #pragma unroll
    for (int n = 0; n < 4; ++n) bv[n] = bias[wc * 64 + n * 16 + (lane & 15)];

    int bx = blockIdx.x;
    int NT = (MT_TOT - 1 - bx) / GX + 1;
    STAGE_A(Ag, bx, 0);
    for (int t = 0; t < NT; ++t) {
        int mt = bx + t * GX;
        if (t + 1 < NT) {
            STAGE_A(Ag, bx + (t + 1) * GX, (t + 1) & 1);
            asm volatile("s_waitcnt vmcnt(4)" ::: "memory");
        } else {
            asm volatile("s_waitcnt vmcnt(0)" ::: "memory");
        }
        __syncthreads();
        const us_t* sAc = sA[t & 1];

        f32x4 acc[2][4];
        #pragma unroll
        for (int m = 0; m < 2; ++m)
            #pragma unroll
            for (int n = 0; n < 4; ++n)
                #pragma unroll
                for (int i = 0; i < 4; ++i) acc[m][n][i] = 0.f;

        #pragma unroll
        for (int ks = 0; ks < 8; ++ks) {
            short8 af[2];
            #pragma unroll
            for (int m = 0; m < 2; ++m) {
                int row = wr * 32 + m * 16 + (lane & 15);
                int sl = (ks * 4 + (lane >> 4)) ^ (row & 7);
                af[m] = *reinterpret_cast<const short8*>(&sAc[row * 256 + sl * 8]);
            }
            #pragma unroll
            for (int m = 0; m < 2; ++m)
                #pragma unroll
                for (int n = 0; n < 4; ++n)
                    acc[m][n] = __builtin_amdgcn_mfma_f32_16x16x32_bf16(
                        af[m], wf[n][ks], acc[m][n], 0, 0, 0);
        }

        int mbase = mt * 64;
        #pragma unroll
        for (int n = 0; n < 4; ++n) {
            int col = wc * 64 + n * 16 + (lane & 15);
            #pragma unroll
            for (int m = 0; m < 2; ++m) {
                int row0 = mbase + wr * 32 + m * 16 + ((lane >> 4) << 2);
                #pragma unroll
                for (int j = 0; j < 4; ++j) {
                    int row = row0 + j;
                    if (row < Nn)
                        C[(size_t)row * HIDD + col] =
                            f2bf(fmaxf(acc[m][n][j] + bv[n], 0.f));
                }
            }
        }
        __syncthreads();
    }
}

// ---------------- layer-2 GEMM: M=50000, K=256, N=128; W in registers ----------------
__global__ __launch_bounds__(512) void k_mm2(
    const us_t* __restrict__ hu, const us_t* __restrict__ hp,
    const us_t* __restrict__ wc20, const us_t* __restrict__ wc21,
    const float* __restrict__ bu2, const float* __restrict__ bp2,
    us_t* __restrict__ tu, us_t* __restrict__ tp,
    float* __restrict__ ou, float* __restrict__ op) {
    __shared__ us_t sA[2][64 * 256];
    int tid = threadIdx.x, lane = tid & 63;
    int wv = tid >> 6, wr = wv >> 2, wc = wv & 3;
    int job = blockIdx.y;
    const us_t* Ag = job ? hp : hu;
    const us_t* W = job ? wc21 : wc20;
    const float* bias = job ? bu2 : bp2;
    us_t* T = job ? tp : tu;
    float* O = job ? ou : op;

    short8 wf[2][8];
    #pragma unroll
    for (int n = 0; n < 2; ++n)
        #pragma unroll
        for (int ks = 0; ks < 8; ++ks) {
            int col = wc * 32 + n * 16 + (lane & 15);
            wf[n][ks] = *reinterpret_cast<const short8*>(
                W + (size_t)col * 256 + ks * 32 + (lane >> 4) * 8);
        }
    float bv[2];
    #pragma unroll
    for (int n = 0; n < 2; ++n) {
        int col = wc * 32 + n * 16 + (lane & 15);
        bv[n] = (col >= 64) ? bias[col - 64] : 0.f;
    }

    int bx = blockIdx.x;
    int NT = (MT_TOT - 1 - bx) / GX + 1;
    STAGE_A(Ag, bx, 0);
    for (int t = 0; t < NT; ++t) {
        int mt = bx + t * GX;
        if (t + 1 < NT) {
            STAGE_A(Ag, bx + (t + 1) * GX, (t + 1) & 1);
            asm volatile("s_waitcnt vmcnt(4)" ::: "memory");
        } else {
            asm volatile("s_waitcnt vmcnt(0)" ::: "memory");
        }
        __syncthreads();
        const us_t* sAc = sA[t & 1];

        f32x4 acc[2][2];
        #pragma unroll
        for (int m = 0; m < 2; ++m)
            #pragma unroll
            for (int n = 0; n < 2; ++n)
                #pragma unroll
                for (int i = 0; i < 4; ++i) acc[m][n][i] = 0.f;

        #pragma unroll
        for (int ks = 0; ks < 8; ++ks) {
            short8 af[2];
            #pragma unroll
            for (int m = 0; m < 2; ++m) {
                int row = wr * 32 + m * 16 + (lane & 15);
                int sl = (ks * 4 + (lane >> 4)) ^ (row & 7);
                af[m] = *reinterpret_cast<const short8*>(&sAc[row * 256 + sl * 8]);
            }
            #pragma unroll
            for (int m = 0; m < 2; ++m)
                #pragma unroll
                for (int n = 0; n < 2; ++n)
                    acc[m][n] = __builtin_amdgcn_mfma_f32_16x16x32_bf16(
                        af[m], wf[n][ks], acc[m][n], 0, 0, 0);
        }

        int mbase = mt * 64;
        #pragma unroll
        for (int n = 0; n < 2; ++n) {
            int col = wc * 32 + n * 16 + (lane & 15);
            bool top = col < 64;
            int cc = top ? col : col - 64;
            #pragma unroll
            for (int m = 0; m < 2; ++m) {
                int row0 = mbase + wr * 32 + m * 16 + ((lane >> 4) << 2);
                #pragma unroll
                for (int j = 0; j < 4; ++j) {
                    int row = row0 + j;
                    if (row >= Nn) continue;
                    float v = acc[m][n][j] + bv[n];
                    if (top) T[(size_t)row * 64 + cc] = f2bf(v);
                    else     O[(size_t)row * 64 + cc] = v;
                }
            }
        }
        __syncthreads();
    }
}

// ---------------- launch ----------------
extern "C" void kernel_launch(void* const* d_in, const int* in_sizes, int n_in,
                              void* d_out, int out_size, void* d_ws, size_t ws_size,
                              hipStream_t stream) {
    const float* x_user    = (const float*)d_in[0];
    const float* x_product = (const float*)d_in[1];
    const int*   ei        = (const int*)d_in[2];
    const float* w_u1_l = (const float*)d_in[3];
    const float* b_u1   = (const float*)d_in[4];
    const float* w_u1_r = (const float*)d_in[5];
    const float* w_p1_l = (const float*)d_in[6];
    const float* b_p1   = (const float*)d_in[7];
    const float* w_p1_r = (const float*)d_in[8];
    const float* w_u2_l = (const float*)d_in[9];
    const float* b_u2   = (const float*)d_in[10];
    const float* w_u2_r = (const float*)d_in[11];
    const float* w_p2_l = (const float*)d_in[12];
    const float* b_p2   = (const float*)d_in[13];
    const float* w_p2_r = (const float*)d_in[14];

    float* out_u = (float*)d_out;
    float* out_p = out_u + (size_t)Nn * CLSS;

    char* w = (char*)d_ws;
    int* bin_cnt  = (int*)w; w += (size_t)2 * NBIN * 4;
    int* off  = (int*)w;  w += (size_t)2 * Nn * 4;
    int* cnt  = (int*)w;  w += (size_t)2 * Nn * 4;
    int* src_p = (int*)w; w += (size_t)Ee * 4;
    int* src_u = (int*)w; w += (size_t)Ee * 4;
    uint_t* ent_p = (uint_t*)w; w += (size_t)NBIN * BCAP * 4;
    uint_t* ent_u = (uint_t*)w; w += (size_t)NBIN * BCAP * 4;
    uintptr_t a = (uintptr_t)w; a = (a + 255) & ~(uintptr_t)255; w = (char*)a;
    us_t* cu   = (us_t*)w; w += (size_t)Nn * 256 * 2;   // [mean_u | x_prod]
    us_t* cp   = (us_t*)w; w += (size_t)Nn * 256 * 2;   // [mean_p | x_user]
    uint_t* xf8u = (uint_t*)w; w += (size_t)Nn * FIN;
    uint_t* xf8p = (uint_t*)w; w += (size_t)Nn * FIN;
    us_t* h_u  = (us_t*)w; w += (size_t)Nn * HIDD * 2;
    us_t* h_p  = (us_t*)w; w += (size_t)Nn * HIDD * 2;
    us_t* tbuf_u = (us_t*)w; w += (size_t)Nn * CLSS * 2;
    us_t* tbuf_p = (us_t*)w; w += (size_t)Nn * CLSS * 2;
    us_t* wc10 = (us_t*)w; w += (size_t)256 * 256 * 2;
    us_t* wc11 = (us_t*)w; w += (size_t)256 * 256 * 2;
    us_t* wc20 = (us_t*)w; w += (size_t)128 * 256 * 2;
    us_t* wc21 = (us_t*)w; w += (size_t)128 * 256 * 2;

    // ---- front-end: zero bin counters, then bin || cvtw || cvtx in one launch ----
    hipMemsetAsync(bin_cnt, 0, (size_t)2 * NBIN * 4, stream);
    k_front<<<NEB + 96 + 512, 512, 0, stream>>>(
        ei, x_user, x_product,
        w_u1_l, w_u1_r, w_p1_l, w_p1_r, w_u2_l, w_u2_r, w_p2_l, w_p2_r,
        cu, cp, xf8u, xf8p, wc10, wc11, wc20, wc21,
        bin_cnt, ent_p, ent_u);
    dim3 gsc(NBIN, 2);
    k_scatter<<<gsc, 512, 0, stream>>>(ent_p, ent_u, bin_cnt,
                                       off, cnt, src_p, src_u);

    // ---- layer 1 ----
    dim3 ga1((Nn + 31) / 32, 2);
    k_agg1<<<ga1, 256, 0, stream>>>((const uint4*)xf8u, (const uint4*)xf8p,
                                    off, cnt, src_p, src_u, cu, cp);
    dim3 g1(GX, 2);
    k_mm1<<<g1, 512, 0, stream>>>(cu, cp, wc10, wc11, b_u1, b_p1, h_u, h_p);

    // ---- layer 2 ----
    dim3 g2(GX, 2);
    k_mm2<<<g2, 512, 0, stream>>>(h_u, h_p, wc20, wc21, b_u2, b_p2,
                                  tbuf_u, tbuf_p, out_u, out_p);
    dim3 ga2((Nn + 31) / 32, 2);
    k_agg2<<<ga2, 256, 0, stream>>>((const uint4*)tbuf_u, (const uint4*)tbuf_p,
                                    off, cnt, src_p, src_u, out_u, out_p);
}

// Round 12
// 179.827 us; speedup vs baseline: 1.2422x; 1.0176x over previous
//
#include <hip/hip_runtime.h>
#include <stdint.h>

#define Nn 50000
#define Ee 800000
#define FIN 128
#define HIDD 256
#define CLSS 64

#define NBIN 98          // ceil(50000 / 512)
#define BSH 9
#define BINSZ 512
#define BCAP 16384
#define EPB 2048
#define NEB ((Ee + EPB - 1) / EPB)   // 391

#define MT_TOT 782       // ceil(50000/64)
#define GX 112           // M-group blocks per job

#define SHP 264          // padded sH row stride (us_t): 528B = 33*16, 16B-aligned

typedef unsigned int uint_t;
typedef unsigned short us_t;
typedef __attribute__((ext_vector_type(8))) short short8;
typedef __attribute__((ext_vector_type(4))) float f32x4;
typedef __attribute__((ext_vector_type(2))) float f32x2;

__device__ inline float bflo(uint_t v) { union { uint_t u; float f; } c; c.u = v << 16; return c.f; }
__device__ inline float bfhi(uint_t v) { union { uint_t u; float f; } c; c.u = v & 0xffff0000u; return c.f; }
__device__ inline us_t f2bf(float f) {
    union { float f; uint_t u; } c; c.f = f;
    uint_t u = c.u;
    u += 0x7fffu + ((u >> 16) & 1u);
    return (us_t)(u >> 16);
}

#define GLOAD(gp, lp)                                                      \
    __builtin_amdgcn_global_load_lds(                                      \
        (const __attribute__((address_space(1))) unsigned int*)(gp),       \
        (__attribute__((address_space(3))) unsigned int*)(lp), 16, 0, 0)

// ================= merged front-end: k_bin || cvtw || cvtx =================
__global__ __launch_bounds__(512) void k_front(
    const int* __restrict__ ei,
    const float* __restrict__ xu, const float* __restrict__ xp,
    const float* __restrict__ w1, const float* __restrict__ w2,
    const float* __restrict__ w3, const float* __restrict__ w4,
    const float* __restrict__ w5, const float* __restrict__ w6,
    const float* __restrict__ w7, const float* __restrict__ w8,
    us_t* __restrict__ cu, us_t* __restrict__ cp,
    uint_t* __restrict__ f8u, uint_t* __restrict__ f8p,
    us_t* __restrict__ wc10, us_t* __restrict__ wc11,
    us_t* __restrict__ wc20, us_t* __restrict__ wc21,
    int* __restrict__ bin_cnt,
    uint_t* __restrict__ ent_p, uint_t* __restrict__ ent_u) {
    __shared__ int hist[2 * NBIN];
    __shared__ int base[2 * NBIN];
    int bx = blockIdx.x, tid = threadIdx.x;

    if (bx < NEB) {
        int e0 = bx * EPB;
        int n = Ee - e0; if (n > EPB) n = EPB;
        for (int i = tid; i < 2 * NBIN; i += 512) hist[i] = 0;
        __syncthreads();
        for (int i = tid; i < n; i += 512) {
            int u = ei[e0 + i], p = ei[Ee + e0 + i];
            atomicAdd(&hist[p >> BSH], 1);
            atomicAdd(&hist[NBIN + (u >> BSH)], 1);
        }
        __syncthreads();
        for (int i = tid; i < 2 * NBIN; i += 512) {
            int c = hist[i];
            base[i] = c ? atomicAdd(&bin_cnt[i], c) : 0;
        }
        __syncthreads();
        for (int i = tid; i < 2 * NBIN; i += 512) hist[i] = base[i];
        __syncthreads();
        for (int i = tid; i < n; i += 512) {
            int u = ei[e0 + i], p = ei[Ee + e0 + i];
            int bp = p >> BSH, bu = u >> BSH;
            int rp = atomicAdd(&hist[bp], 1);
            if (rp < BCAP)
                ent_p[(size_t)bp * BCAP + rp] = ((uint_t)(p & (BINSZ - 1)) << 16) | (uint_t)u;
            int ru = atomicAdd(&hist[NBIN + bu], 1);
            if (ru < BCAP)
                ent_u[(size_t)bu * BCAP + ru] = ((uint_t)(u & (BINSZ - 1)) << 16) | (uint_t)p;
        }
    } else if (bx < NEB + 96) {
        int i = (bx - NEB) * 512 + tid;
        const float* wp; us_t* dst;
        if (i < 32768) {
            int seg = i >> 13; int loc = i & 8191;
            int row = loc >> 5, col = (loc & 31) * 4;
            switch (seg) {
                case 0: wp = w1; dst = wc10 + (size_t)row * 256 + col; break;
                case 1: wp = w2; dst = wc10 + (size_t)row * 256 + 128 + col; break;
                case 2: wp = w3; dst = wc11 + (size_t)row * 256 + col; break;
                default: wp = w4; dst = wc11 + (size_t)row * 256 + 128 + col; break;
            }
            float4 v = reinterpret_cast<const float4*>(wp)[i & 8191];
            ushort4 o;
            o.x = f2bf(v.x); o.y = f2bf(v.y); o.z = f2bf(v.z); o.w = f2bf(v.w);
            *reinterpret_cast<ushort4*>(dst) = o;
        } else {
            int j = i - 32768;
            int seg = j >> 12; int loc = j & 4095;
            switch (seg) {
                case 0: wp = w5; dst = wc20; break;
                case 1: wp = w6; dst = wc21 + 64 * 256; break;
                case 2: wp = w7; dst = wc21; break;
                default: wp = w8; dst = wc20 + 64 * 256; break;
            }
            float4 v = reinterpret_cast<const float4*>(wp)[loc];
            ushort4 o;
            o.x = f2bf(v.x); o.y = f2bf(v.y); o.z = f2bf(v.z); o.w = f2bf(v.w);
            reinterpret_cast<ushort4*>(dst)[loc] = o;
        }
    } else {
        int bcx = bx - NEB - 96;
        int side = bcx & 1;
        const float* in = side ? xp : xu;
        us_t* comb = side ? cu : cp;
        uint_t* o8 = side ? f8p : f8u;
        const int n4 = (Nn * FIN) / 4;
        int i = (bcx >> 1) * 512 + tid;
        int stride = 256 * 512;
        for (; i < n4; i += stride) {
            float4 v = reinterpret_cast<const float4*>(in)[i];
            ushort4 o;
            o.x = f2bf(v.x); o.y = f2bf(v.y); o.z = f2bf(v.z); o.w = f2bf(v.w);
            int node = i >> 5;
            int col = (i & 31) * 4;
            *reinterpret_cast<ushort4*>(comb + (size_t)node * 256 + 128 + col) = o;
            int pk = __builtin_amdgcn_cvt_pk_fp8_f32(v.x, v.y, 0, false);
            pk = __builtin_amdgcn_cvt_pk_fp8_f32(v.z, v.w, pk, true);
            o8[i] = (uint_t)pk;
        }
    }
}

// ---------------- per-bin scatter with inline bin-base scan ----------------
__global__ __launch_bounds__(512) void k_scatter(
    const uint_t* __restrict__ ent_p, const uint_t* __restrict__ ent_u,
    const int* __restrict__ bin_cnt,
    int* __restrict__ off, int* __restrict__ cnt,
    int* __restrict__ src_p, int* __restrict__ src_u) {
    __shared__ int ca[BINSZ];
    __shared__ int cb[BINSZ];
    __shared__ int bb[128];
    int side = blockIdx.y, b = blockIdx.x, t = threadIdx.x;
    const uint_t* E = (side ? ent_u : ent_p) + (size_t)b * BCAP;
    int* src = side ? src_u : src_p;

    if (t < 128) {
        int v = 0;
        if (t < NBIN) { v = bin_cnt[side * NBIN + t]; if (v > BCAP) v = BCAP; }
        bb[t] = v;
    }
    __syncthreads();
    #pragma unroll
    for (int d = 1; d < 128; d <<= 1) {
        int x = 0;
        if (t < 128 && t >= d) x = bb[t - d];
        __syncthreads();
        if (t < 128) bb[t] += x;
        __syncthreads();
    }
    int nb = bin_cnt[side * NBIN + b]; if (nb > BCAP) nb = BCAP;
    int base = bb[b] - nb;

    ca[t] = 0;
    __syncthreads();
    for (int i = t; i < nb; i += 512)
        atomicAdd(&ca[E[i] >> 16], 1);
    __syncthreads();
    int v = ca[t];
    int* A = ca; int* B = cb;
    #pragma unroll
    for (int d = 1; d < BINSZ; d <<= 1) {
        int x = A[t] + ((t >= d) ? A[t - d] : 0);
        B[t] = x;
        __syncthreads();
        int* tmp = A; A = B; B = tmp;
    }
    int excl = A[t] - v;
    B[t] = excl;
    __syncthreads();
    for (int i = t; i < nb; i += 512) {
        uint_t e = E[i];
        int sl = atomicAdd(&B[e >> 16], 1);
        src[base + sl] = (int)(e & 0xffffu);
    }
    int d = (b << BSH) + t;
    if (d < Nn) {
        off[side * Nn + d] = base + excl;
        cnt[side * Nn + d] = v;
    }
}

// ---------------- layer-1 mean aggregation: 8 lanes x uint4 per fp8 row ----------------
__global__ __launch_bounds__(256) void k_agg1(
    const uint4* __restrict__ xu8, const uint4* __restrict__ xp8,
    const int* __restrict__ off, const int* __restrict__ cnt,
    const int* __restrict__ src_p, const int* __restrict__ src_u,
    us_t* __restrict__ cu, us_t* __restrict__ cp) {
    int side = blockIdx.y;
    const uint4* X = side ? xp8 : xu8;
    const int* of = off + side * Nn;
    const int* cn = cnt + side * Nn;
    const int* sr = side ? src_u : src_p;
    us_t* out = side ? cp : cu;

    int node = blockIdx.x * 32 + (threadIdx.x >> 3);
    if (node >= Nn) return;
    int l = threadIdx.x & 7;
    int s = of[node], c = cn[node];
    float ac[16];
    #pragma unroll
    for (int i = 0; i < 16; ++i) ac[i] = 0.f;

    int j = 0;
    for (; j + 8 <= c; j += 8) {
        int ss[8];
        #pragma unroll
        for (int q = 0; q < 8; ++q) ss[q] = sr[s + j + q];
        uint4 vv[8];
        #pragma unroll
        for (int q = 0; q < 8; ++q) vv[q] = X[(size_t)ss[q] * 8 + l];
        #pragma unroll
        for (int q = 0; q < 8; ++q) {
            const uint_t* pw = reinterpret_cast<const uint_t*>(&vv[q]);
            #pragma unroll
            for (int h = 0; h < 4; ++h) {
                f32x2 plo = __builtin_amdgcn_cvt_pk_f32_fp8((int)pw[h], false);
                f32x2 phi = __builtin_amdgcn_cvt_pk_f32_fp8((int)pw[h], true);
                ac[h * 4 + 0] += plo[0]; ac[h * 4 + 1] += plo[1];
                ac[h * 4 + 2] += phi[0]; ac[h * 4 + 3] += phi[1];
            }
        }
    }
    for (; j < c; ++j) {
        uint4 v0 = X[(size_t)sr[s + j] * 8 + l];
        const uint_t* pw = reinterpret_cast<const uint_t*>(&v0);
        #pragma unroll
        for (int h = 0; h < 4; ++h) {
            f32x2 plo = __builtin_amdgcn_cvt_pk_f32_fp8((int)pw[h], false);
            f32x2 phi = __builtin_amdgcn_cvt_pk_f32_fp8((int)pw[h], true);
            ac[h * 4 + 0] += plo[0]; ac[h * 4 + 1] += plo[1];
            ac[h * 4 + 2] += phi[0]; ac[h * 4 + 3] += phi[1];
        }
    }
    float inv = 1.0f / fmaxf((float)c, 1.0f);
    uint_t ow[8];
    #pragma unroll
    for (int i = 0; i < 8; ++i)
        ow[i] = (uint_t)f2bf(ac[2 * i] * inv) | ((uint_t)f2bf(ac[2 * i + 1] * inv) << 16);
    uint4* dst = reinterpret_cast<uint4*>(out + (size_t)node * 256 + l * 16);
    uint4 o0 = {ow[0], ow[1], ow[2], ow[3]};
    uint4 o1 = {ow[4], ow[5], ow[6], ow[7]};
    dst[0] = o0;
    dst[1] = o1;
}

// ---------------- layer-2 mean aggregation: 8 lanes x uint4 per bf16 row ----------------
__global__ __launch_bounds__(256) void k_agg2(
    const uint4* __restrict__ tu, const uint4* __restrict__ tp,
    const int* __restrict__ off, const int* __restrict__ cnt,
    const int* __restrict__ src_p, const int* __restrict__ src_u,
    float* __restrict__ ou, float* __restrict__ op) {
    int side = blockIdx.y;
    const uint4* T = side ? tp : tu;
    const int* of = off + side * Nn;
    const int* cn = cnt + side * Nn;
    const int* sr = side ? src_u : src_p;
    float* out = side ? op : ou;

    int node = blockIdx.x * 32 + (threadIdx.x >> 3);
    if (node >= Nn) return;
    int l = threadIdx.x & 7;
    int s = of[node], c = cn[node];
    float ac[8];
    #pragma unroll
    for (int i = 0; i < 8; ++i) ac[i] = 0.f;

    int j = 0;
    for (; j + 8 <= c; j += 8) {
        int ss[8];
        #pragma unroll
        for (int q = 0; q < 8; ++q) ss[q] = sr[s + j + q];
        uint4 vv[8];
        #pragma unroll
        for (int q = 0; q < 8; ++q) vv[q] = T[(size_t)ss[q] * 8 + l];
        #pragma unroll
        for (int q = 0; q < 8; ++q) {
            const uint_t* pw = reinterpret_cast<const uint_t*>(&vv[q]);
            #pragma unroll
            for (int h = 0; h < 4; ++h) {
                ac[h * 2 + 0] += bflo(pw[h]);
                ac[h * 2 + 1] += bfhi(pw[h]);
            }
        }
    }
    for (; j < c; ++j) {
        uint4 v0 = T[(size_t)sr[s + j] * 8 + l];
        const uint_t* pw = reinterpret_cast<const uint_t*>(&v0);
        #pragma unroll
        for (int h = 0; h < 4; ++h) {
            ac[h * 2 + 0] += bflo(pw[h]);
            ac[h * 2 + 1] += bfhi(pw[h]);
        }
    }
    float inv = 1.0f / fmaxf((float)c, 1.0f);
    float4* po = reinterpret_cast<float4*>(out + (size_t)node * 64) + l * 2;
    float4 p0 = po[0], p1 = po[1];
    p0.x += ac[0] * inv; p0.y += ac[1] * inv; p0.z += ac[2] * inv; p0.w += ac[3] * inv;
    p1.x += ac[4] * inv; p1.y += ac[5] * inv; p1.z += ac[6] * inv; p1.w += ac[7] * inv;
    po[0] = p0; po[1] = p1;
}

// ---------------- A-tile stage: 64 rows x 256 K bf16 = 32 KB, XOR-swizzled ----------------
#define STAGE_A(Ag, mt, b)                                                          \
    {                                                                               \
        int base_ = (mt) * 64;                                                      \
        _Pragma("unroll")                                                           \
        for (int ii = 0; ii < 4; ++ii) {                                            \
            int s_ = ii * 512 + tid;                                                \
            int row_ = s_ >> 5, ks_ = s_ & 31;                                      \
            int ksl_ = ks_ ^ (row_ & 7);                                            \
            int gr_ = base_ + row_; if (gr_ >= Nn) gr_ = Nn - 1;                    \
            GLOAD((Ag) + (size_t)gr_ * 256 + ksl_ * 8, &sA[b][(s_ - lane) * 8]);    \
        }                                                                           \
    }

// ================= fused layer-1 + layer-2 GEMM =================
// job0: A=cu --W1(wc10)--> h_u tile (relu+b_u1, bf16, LDS only)
//               --W2(wc20)--> cols0-63: tu (bf16), cols64-127: op (f32 + b_p2)
// job1: A=cp --W1(wc11)--> h_p --W2(wc21)--> tp | ou (+ b_u2)
// h never touches global memory.
__global__ __launch_bounds__(512) void k_mmf(
    const us_t* __restrict__ cu, const us_t* __restrict__ cp,
    const us_t* __restrict__ wc10, const us_t* __restrict__ wc11,
    const us_t* __restrict__ wc20, const us_t* __restrict__ wc21,
    const float* __restrict__ bu1, const float* __restrict__ bp1,
    const float* __restrict__ bu2, const float* __restrict__ bp2,
    us_t* __restrict__ tu, us_t* __restrict__ tp,
    float* __restrict__ ou, float* __restrict__ op) {
    __shared__ us_t sA[2][64 * 256];
    __shared__ us_t sH[64 * SHP];
    int tid = threadIdx.x, lane = tid & 63;
    int wv = tid >> 6, wr = wv >> 2, wc = wv & 3;
    int job = blockIdx.y;
    const us_t* Ag = job ? cp : cu;
    const us_t* W1 = job ? wc11 : wc10;
    const us_t* W2 = job ? wc21 : wc20;
    const float* b1 = job ? bp1 : bu1;
    const float* b2 = job ? bu2 : bp2;
    us_t* T = job ? tp : tu;
    float* O = job ? ou : op;

    // W1 frags: 64 out-cols per wave, K=256
    short8 wf1[4][8];
    #pragma unroll
    for (int n = 0; n < 4; ++n)
        #pragma unroll
        for (int ks = 0; ks < 8; ++ks) {
            int col = wc * 64 + n * 16 + (lane & 15);
            wf1[n][ks] = *reinterpret_cast<const short8*>(
                W1 + (size_t)col * 256 + ks * 32 + (lane >> 4) * 8);
        }
    float bv1[4];
    #pragma unroll
    for (int n = 0; n < 4; ++n) bv1[n] = b1[wc * 64 + n * 16 + (lane & 15)];

    // W2 frags: 32 out-cols per wave (128 total), K=256
    short8 wf2[2][8];
    #pragma unroll
    for (int n = 0; n < 2; ++n)
        #pragma unroll
        for (int ks = 0; ks < 8; ++ks) {
            int col = wc * 32 + n * 16 + (lane & 15);
            wf2[n][ks] = *reinterpret_cast<const short8*>(
                W2 + (size_t)col * 256 + ks * 32 + (lane >> 4) * 8);
        }
    float bv2[2];
    #pragma unroll
    for (int n = 0; n < 2; ++n) {
        int col = wc * 32 + n * 16 + (lane & 15);
        bv2[n] = (col >= 64) ? b2[col - 64] : 0.f;
    }

    int bx = blockIdx.x;
    int NT = (MT_TOT - 1 - bx) / GX + 1;
    STAGE_A(Ag, bx, 0);
    for (int t = 0; t < NT; ++t) {
        int mt = bx + t * GX;
        if (t + 1 < NT) {
            STAGE_A(Ag, bx + (t + 1) * GX, (t + 1) & 1);
            asm volatile("s_waitcnt vmcnt(4)" ::: "memory");
        } else {
            asm volatile("s_waitcnt vmcnt(0)" ::: "memory");
        }
        __syncthreads();   // sA[cur] ready; all prior-tile sH readers done
        const us_t* sAc = sA[t & 1];

        // ---- layer-1 MFMAs ----
        f32x4 acc1[2][4];
        #pragma unroll
        for (int m = 0; m < 2; ++m)
            #pragma unroll
            for (int n = 0; n < 4; ++n)
                #pragma unroll
                for (int i = 0; i < 4; ++i) acc1[m][n][i] = 0.f;

        #pragma unroll
        for (int ks = 0; ks < 8; ++ks) {
            short8 af[2];
            #pragma unroll
            for (int m = 0; m < 2; ++m) {
                int row = wr * 32 + m * 16 + (lane & 15);
                int sl = (ks * 4 + (lane >> 4)) ^ (row & 7);
                af[m] = *reinterpret_cast<const short8*>(&sAc[row * 256 + sl * 8]);
            }
            #pragma unroll
            for (int m = 0; m < 2; ++m)
                #pragma unroll
                for (int n = 0; n < 4; ++n)
                    acc1[m][n] = __builtin_amdgcn_mfma_f32_16x16x32_bf16(
                        af[m], wf1[n][ks], acc1[m][n], 0, 0, 0);
        }

        // ---- h tile -> LDS (bf16, relu+bias), row-major padded ----
        #pragma unroll
        for (int n = 0; n < 4; ++n) {
            int col = wc * 64 + n * 16 + (lane & 15);
            #pragma unroll
            for (int m = 0; m < 2; ++m) {
                int r0 = wr * 32 + m * 16 + ((lane >> 4) << 2);
                #pragma unroll
                for (int j = 0; j < 4; ++j)
                    sH[(r0 + j) * SHP + col] =
                        f2bf(fmaxf(acc1[m][n][j] + bv1[n], 0.f));
            }
        }
        __syncthreads();   // sH complete

        // ---- layer-2 MFMAs ----
        f32x4 acc2[2][2];
        #pragma unroll
        for (int m = 0; m < 2; ++m)
            #pragma unroll
            for (int n = 0; n < 2; ++n)
                #pragma unroll
                for (int i = 0; i < 4; ++i) acc2[m][n][i] = 0.f;

        #pragma unroll
        for (int ks = 0; ks < 8; ++ks) {
            short8 af2[2];
            #pragma unroll
            for (int m = 0; m < 2; ++m) {
                int row = wr * 32 + m * 16 + (lane & 15);
                af2[m] = *reinterpret_cast<const short8*>(
                    &sH[row * SHP + ks * 32 + (lane >> 4) * 8]);
            }
            #pragma unroll
            for (int m = 0; m < 2; ++m)
                #pragma unroll
                for (int n = 0; n < 2; ++n)
                    acc2[m][n] = __builtin_amdgcn_mfma_f32_16x16x32_bf16(
                        af2[m], wf2[n][ks], acc2[m][n], 0, 0, 0);
        }

        int mbase = mt * 64;
        #pragma unroll
        for (int n = 0; n < 2; ++n) {
            int col = wc * 32 + n * 16 + (lane & 15);
            bool top = col < 64;
            int cc = top ? col : col - 64;
            #pragma unroll
            for (int m = 0; m < 2; ++m) {
                int row0 = mbase + wr * 32 + m * 16 + ((lane >> 4) << 2);
                #pragma unroll
                for (int j = 0; j < 4; ++j) {
                    int row = row0 + j;
                    if (row >= Nn) continue;
                    float v = acc2[m][n][j] + bv2[n];
                    if (top) T[(size_t)row * 64 + cc] = f2bf(v);
                    else     O[(size_t)row * 64 + cc] = v;
                }
            }
        }
        // next iteration's top barrier separates these sH reads from the next writes
    }
}

// ---------------- launch ----------------
extern "C" void kernel_launch(void* const* d_in, const int* in_sizes, int n_in,
                              void* d_out, int out_size, void* d_ws, size_t ws_size,
                              hipStream_t stream) {
    const float* x_user    = (const float*)d_in[0];
    const float* x_product = (const float*)d_in[1];
    const int*   ei        = (const int*)d_in[2];
    const float* w_u1_l = (const float*)d_in[3];
    const float* b_u1   = (const float*)d_in[4];
    const float* w_u1_r = (const float*)d_in[5];
    const float* w_p1_l = (const float*)d_in[6];
    const float* b_p1   = (const float*)d_in[7];
    const float* w_p1_r = (const float*)d_in[8];
    const float* w_u2_l = (const float*)d_in[9];
    const float* b_u2   = (const float*)d_in[10];
    const float* w_u2_r = (const float*)d_in[11];
    const float* w_p2_l = (const float*)d_in[12];
    const float* b_p2   = (const float*)d_in[13];
    const float* w_p2_r = (const float*)d_in[14];

    float* out_u = (float*)d_out;
    float* out_p = out_u + (size_t)Nn * CLSS;

    char* w = (char*)d_ws;
    int* bin_cnt  = (int*)w; w += (size_t)2 * NBIN * 4;
    int* off  = (int*)w;  w += (size_t)2 * Nn * 4;
    int* cnt  = (int*)w;  w += (size_t)2 * Nn * 4;
    int* src_p = (int*)w; w += (size_t)Ee * 4;
    int* src_u = (int*)w; w += (size_t)Ee * 4;
    uint_t* ent_p = (uint_t*)w; w += (size_t)NBIN * BCAP * 4;
    uint_t* ent_u = (uint_t*)w; w += (size_t)NBIN * BCAP * 4;
    uintptr_t a = (uintptr_t)w; a = (a + 255) & ~(uintptr_t)255; w = (char*)a;
    us_t* cu   = (us_t*)w; w += (size_t)Nn * 256 * 2;   // [mean_u | x_prod]
    us_t* cp   = (us_t*)w; w += (size_t)Nn * 256 * 2;   // [mean_p | x_user]
    uint_t* xf8u = (uint_t*)w; w += (size_t)Nn * FIN;
    uint_t* xf8p = (uint_t*)w; w += (size_t)Nn * FIN;
    us_t* tbuf_u = (us_t*)w; w += (size_t)Nn * CLSS * 2;
    us_t* tbuf_p = (us_t*)w; w += (size_t)Nn * CLSS * 2;
    us_t* wc10 = (us_t*)w; w += (size_t)256 * 256 * 2;
    us_t* wc11 = (us_t*)w; w += (size_t)256 * 256 * 2;
    us_t* wc20 = (us_t*)w; w += (size_t)128 * 256 * 2;
    us_t* wc21 = (us_t*)w; w += (size_t)128 * 256 * 2;

    // ---- front-end: zero bin counters, then bin || cvtw || cvtx in one launch ----
    hipMemsetAsync(bin_cnt, 0, (size_t)2 * NBIN * 4, stream);
    k_front<<<NEB + 96 + 512, 512, 0, stream>>>(
        ei, x_user, x_product,
        w_u1_l, w_u1_r, w_p1_l, w_p1_r, w_u2_l, w_u2_r, w_p2_l, w_p2_r,
        cu, cp, xf8u, xf8p, wc10, wc11, wc20, wc21,
        bin_cnt, ent_p, ent_u);
    dim3 gsc(NBIN, 2);
    k_scatter<<<gsc, 512, 0, stream>>>(ent_p, ent_u, bin_cnt,
                                       off, cnt, src_p, src_u);

    // ---- layer 1 aggregation ----
    dim3 ga1((Nn + 31) / 32, 2);
    k_agg1<<<ga1, 256, 0, stream>>>((const uint4*)xf8u, (const uint4*)xf8p,
                                    off, cnt, src_p, src_u, cu, cp);

    // ---- fused layer-1 + layer-2 GEMM ----
    dim3 g1(GX, 2);
    k_mmf<<<g1, 512, 0, stream>>>(cu, cp, wc10, wc11, wc20, wc21,
                                  b_u1, b_p1, b_u2, b_p2,
                                  tbuf_u, tbuf_p, out_u, out_p);

    // ---- layer 2 aggregation ----
    dim3 ga2((Nn + 31) / 32, 2);
    k_agg2<<<ga2, 256, 0, stream>>>((const uint4*)tbuf_u, (const uint4*)tbuf_p,
                                    off, cnt, src_p, src_u, out_u, out_p);
}

// Round 13
// 176.133 us; speedup vs baseline: 1.2682x; 1.0210x over previous
//
#include <hip/hip_runtime.h>
#include <stdint.h>

#define Nn 50000
#define Ee 800000
#define FIN 128
#define HIDD 256
#define CLSS 64

#define NBIN 98          // ceil(50000 / 512)
#define BSH 9
#define BINSZ 512
#define BCAP 16384
#define EPB 2048
#define NEB ((Ee + EPB - 1) / EPB)   // 391

#define MT32 1563        // ceil(50000/32)
#define GXF 256          // M-group blocks per job for fused GEMM (512 blocks total)

#define SHP 264          // padded sH row stride (us_t)

typedef unsigned int uint_t;
typedef unsigned short us_t;
typedef __attribute__((ext_vector_type(8))) short short8;
typedef __attribute__((ext_vector_type(4))) float f32x4;
typedef __attribute__((ext_vector_type(2))) float f32x2;

__device__ inline float bflo(uint_t v) { union { uint_t u; float f; } c; c.u = v << 16; return c.f; }
__device__ inline float bfhi(uint_t v) { union { uint_t u; float f; } c; c.u = v & 0xffff0000u; return c.f; }
__device__ inline us_t f2bf(float f) {
    union { float f; uint_t u; } c; c.f = f;
    uint_t u = c.u;
    u += 0x7fffu + ((u >> 16) & 1u);
    return (us_t)(u >> 16);
}

#define GLOAD(gp, lp)                                                      \
    __builtin_amdgcn_global_load_lds(                                      \
        (const __attribute__((address_space(1))) unsigned int*)(gp),       \
        (__attribute__((address_space(3))) unsigned int*)(lp), 16, 0, 0)

// ================= merged front-end: k_bin || cvtw || cvtx =================
__global__ __launch_bounds__(512) void k_front(
    const int* __restrict__ ei,
    const float* __restrict__ xu, const float* __restrict__ xp,
    const float* __restrict__ w1, const float* __restrict__ w2,
    const float* __restrict__ w3, const float* __restrict__ w4,
    const float* __restrict__ w5, const float* __restrict__ w6,
    const float* __restrict__ w7, const float* __restrict__ w8,
    us_t* __restrict__ cu, us_t* __restrict__ cp,
    uint_t* __restrict__ f8u, uint_t* __restrict__ f8p,
    us_t* __restrict__ wc10, us_t* __restrict__ wc11,
    us_t* __restrict__ wc20, us_t* __restrict__ wc21,
    int* __restrict__ bin_cnt,
    uint_t* __restrict__ ent_p, uint_t* __restrict__ ent_u) {
    __shared__ int hist[2 * NBIN];
    __shared__ int base[2 * NBIN];
    int bx = blockIdx.x, tid = threadIdx.x;

    if (bx < NEB) {
        int e0 = bx * EPB;
        int n = Ee - e0; if (n > EPB) n = EPB;
        for (int i = tid; i < 2 * NBIN; i += 512) hist[i] = 0;
        __syncthreads();
        for (int i = tid; i < n; i += 512) {
            int u = ei[e0 + i], p = ei[Ee + e0 + i];
            atomicAdd(&hist[p >> BSH], 1);
            atomicAdd(&hist[NBIN + (u >> BSH)], 1);
        }
        __syncthreads();
        for (int i = tid; i < 2 * NBIN; i += 512) {
            int c = hist[i];
            base[i] = c ? atomicAdd(&bin_cnt[i], c) : 0;
        }
        __syncthreads();
        for (int i = tid; i < 2 * NBIN; i += 512) hist[i] = base[i];
        __syncthreads();
        for (int i = tid; i < n; i += 512) {
            int u = ei[e0 + i], p = ei[Ee + e0 + i];
            int bp = p >> BSH, bu = u >> BSH;
            int rp = atomicAdd(&hist[bp], 1);
            if (rp < BCAP)
                ent_p[(size_t)bp * BCAP + rp] = ((uint_t)(p & (BINSZ - 1)) << 16) | (uint_t)u;
            int ru = atomicAdd(&hist[NBIN + bu], 1);
            if (ru < BCAP)
                ent_u[(size_t)bu * BCAP + ru] = ((uint_t)(u & (BINSZ - 1)) << 16) | (uint_t)p;
        }
    } else if (bx < NEB + 96) {
        int i = (bx - NEB) * 512 + tid;
        const float* wp; us_t* dst;
        if (i < 32768) {
            int seg = i >> 13; int loc = i & 8191;
            int row = loc >> 5, col = (loc & 31) * 4;
            switch (seg) {
                case 0: wp = w1; dst = wc10 + (size_t)row * 256 + col; break;
                case 1: wp = w2; dst = wc10 + (size_t)row * 256 + 128 + col; break;
                case 2: wp = w3; dst = wc11 + (size_t)row * 256 + col; break;
                default: wp = w4; dst = wc11 + (size_t)row * 256 + 128 + col; break;
            }
            float4 v = reinterpret_cast<const float4*>(wp)[i & 8191];
            ushort4 o;
            o.x = f2bf(v.x); o.y = f2bf(v.y); o.z = f2bf(v.z); o.w = f2bf(v.w);
            *reinterpret_cast<ushort4*>(dst) = o;
        } else {
            int j = i - 32768;
            int seg = j >> 12; int loc = j & 4095;
            switch (seg) {
                case 0: wp = w5; dst = wc20; break;
                case 1: wp = w6; dst = wc21 + 64 * 256; break;
                case 2: wp = w7; dst = wc21; break;
                default: wp = w8; dst = wc20 + 64 * 256; break;
            }
            float4 v = reinterpret_cast<const float4*>(wp)[loc];
            ushort4 o;
            o.x = f2bf(v.x); o.y = f2bf(v.y); o.z = f2bf(v.z); o.w = f2bf(v.w);
            reinterpret_cast<ushort4*>(dst)[loc] = o;
        }
    } else {
        int bcx = bx - NEB - 96;
        int side = bcx & 1;
        const float* in = side ? xp : xu;
        us_t* comb = side ? cu : cp;
        uint_t* o8 = side ? f8p : f8u;
        const int n4 = (Nn * FIN) / 4;
        int i = (bcx >> 1) * 512 + tid;
        int stride = 256 * 512;
        for (; i < n4; i += stride) {
            float4 v = reinterpret_cast<const float4*>(in)[i];
            ushort4 o;
            o.x = f2bf(v.x); o.y = f2bf(v.y); o.z = f2bf(v.z); o.w = f2bf(v.w);
            int node = i >> 5;
            int col = (i & 31) * 4;
            *reinterpret_cast<ushort4*>(comb + (size_t)node * 256 + 128 + col) = o;
            int pk = __builtin_amdgcn_cvt_pk_fp8_f32(v.x, v.y, 0, false);
            pk = __builtin_amdgcn_cvt_pk_fp8_f32(v.z, v.w, pk, true);
            o8[i] = (uint_t)pk;
        }
    }
}

// ---------------- per-bin scatter with inline bin-base scan ----------------
__global__ __launch_bounds__(512) void k_scatter(
    const uint_t* __restrict__ ent_p, const uint_t* __restrict__ ent_u,
    const int* __restrict__ bin_cnt,
    int* __restrict__ off, int* __restrict__ cnt,
    int* __restrict__ src_p, int* __restrict__ src_u) {
    __shared__ int ca[BINSZ];
    __shared__ int cb[BINSZ];
    __shared__ int bb[128];
    int side = blockIdx.y, b = blockIdx.x, t = threadIdx.x;
    const uint_t* E = (side ? ent_u : ent_p) + (size_t)b * BCAP;
    int* src = side ? src_u : src_p;

    if (t < 128) {
        int v = 0;
        if (t < NBIN) { v = bin_cnt[side * NBIN + t]; if (v > BCAP) v = BCAP; }
        bb[t] = v;
    }
    __syncthreads();
    #pragma unroll
    for (int d = 1; d < 128; d <<= 1) {
        int x = 0;
        if (t < 128 && t >= d) x = bb[t - d];
        __syncthreads();
        if (t < 128) bb[t] += x;
        __syncthreads();
    }
    int nb = bin_cnt[side * NBIN + b]; if (nb > BCAP) nb = BCAP;
    int base = bb[b] - nb;

    ca[t] = 0;
    __syncthreads();
    for (int i = t; i < nb; i += 512)
        atomicAdd(&ca[E[i] >> 16], 1);
    __syncthreads();
    int v = ca[t];
    int* A = ca; int* B = cb;
    #pragma unroll
    for (int d = 1; d < BINSZ; d <<= 1) {
        int x = A[t] + ((t >= d) ? A[t - d] : 0);
        B[t] = x;
        __syncthreads();
        int* tmp = A; A = B; B = tmp;
    }
    int excl = A[t] - v;
    B[t] = excl;
    __syncthreads();
    for (int i = t; i < nb; i += 512) {
        uint_t e = E[i];
        int sl = atomicAdd(&B[e >> 16], 1);
        src[base + sl] = (int)(e & 0xffffu);
    }
    int d = (b << BSH) + t;
    if (d < Nn) {
        off[side * Nn + d] = base + excl;
        cnt[side * Nn + d] = v;
    }
}

// ---------------- layer-1 mean aggregation: 8 lanes x uint4 per fp8 row ----------------
__global__ __launch_bounds__(256) void k_agg1(
    const uint4* __restrict__ xu8, const uint4* __restrict__ xp8,
    const int* __restrict__ off, const int* __restrict__ cnt,
    const int* __restrict__ src_p, const int* __restrict__ src_u,
    us_t* __restrict__ cu, us_t* __restrict__ cp) {
    int side = blockIdx.y;
    const uint4* X = side ? xp8 : xu8;
    const int* of = off + side * Nn;
    const int* cn = cnt + side * Nn;
    const int* sr = side ? src_u : src_p;
    us_t* out = side ? cp : cu;

    int node = blockIdx.x * 32 + (threadIdx.x >> 3);
    if (node >= Nn) return;
    int l = threadIdx.x & 7;
    int s = of[node], c = cn[node];
    float ac[16];
    #pragma unroll
    for (int i = 0; i < 16; ++i) ac[i] = 0.f;

    int j = 0;
    for (; j + 8 <= c; j += 8) {
        int ss[8];
        #pragma unroll
        for (int q = 0; q < 8; ++q) ss[q] = sr[s + j + q];
        uint4 vv[8];
        #pragma unroll
        for (int q = 0; q < 8; ++q) vv[q] = X[(size_t)ss[q] * 8 + l];
        #pragma unroll
        for (int q = 0; q < 8; ++q) {
            const uint_t* pw = reinterpret_cast<const uint_t*>(&vv[q]);
            #pragma unroll
            for (int h = 0; h < 4; ++h) {
                f32x2 plo = __builtin_amdgcn_cvt_pk_f32_fp8((int)pw[h], false);
                f32x2 phi = __builtin_amdgcn_cvt_pk_f32_fp8((int)pw[h], true);
                ac[h * 4 + 0] += plo[0]; ac[h * 4 + 1] += plo[1];
                ac[h * 4 + 2] += phi[0]; ac[h * 4 + 3] += phi[1];
            }
        }
    }
    for (; j < c; ++j) {
        uint4 v0 = X[(size_t)sr[s + j] * 8 + l];
        const uint_t* pw = reinterpret_cast<const uint_t*>(&v0);
        #pragma unroll
        for (int h = 0; h < 4; ++h) {
            f32x2 plo = __builtin_amdgcn_cvt_pk_f32_fp8((int)pw[h], false);
            f32x2 phi = __builtin_amdgcn_cvt_pk_f32_fp8((int)pw[h], true);
            ac[h * 4 + 0] += plo[0]; ac[h * 4 + 1] += plo[1];
            ac[h * 4 + 2] += phi[0]; ac[h * 4 + 3] += phi[1];
        }
    }
    float inv = 1.0f / fmaxf((float)c, 1.0f);
    uint_t ow[8];
    #pragma unroll
    for (int i = 0; i < 8; ++i)
        ow[i] = (uint_t)f2bf(ac[2 * i] * inv) | ((uint_t)f2bf(ac[2 * i + 1] * inv) << 16);
    uint4* dst = reinterpret_cast<uint4*>(out + (size_t)node * 256 + l * 16);
    uint4 o0 = {ow[0], ow[1], ow[2], ow[3]};
    uint4 o1 = {ow[4], ow[5], ow[6], ow[7]};
    dst[0] = o0;
    dst[1] = o1;
}

// ---------------- layer-2 mean aggregation: 8 lanes x uint4 per bf16 row ----------------
__global__ __launch_bounds__(256) void k_agg2(
    const uint4* __restrict__ tu, const uint4* __restrict__ tp,
    const int* __restrict__ off, const int* __restrict__ cnt,
    const int* __restrict__ src_p, const int* __restrict__ src_u,
    float* __restrict__ ou, float* __restrict__ op) {
    int side = blockIdx.y;
    const uint4* T = side ? tp : tu;
    const int* of = off + side * Nn;
    const int* cn = cnt + side * Nn;
    const int* sr = side ? src_u : src_p;
    float* out = side ? op : ou;

    int node = blockIdx.x * 32 + (threadIdx.x >> 3);
    if (node >= Nn) return;
    int l = threadIdx.x & 7;
    int s = of[node], c = cn[node];
    float ac[8];
    #pragma unroll
    for (int i = 0; i < 8; ++i) ac[i] = 0.f;

    int j = 0;
    for (; j + 8 <= c; j += 8) {
        int ss[8];
        #pragma unroll
        for (int q = 0; q < 8; ++q) ss[q] = sr[s + j + q];
        uint4 vv[8];
        #pragma unroll
        for (int q = 0; q < 8; ++q) vv[q] = T[(size_t)ss[q] * 8 + l];
        #pragma unroll
        for (int q = 0; q < 8; ++q) {
            const uint_t* pw = reinterpret_cast<const uint_t*>(&vv[q]);
            #pragma unroll
            for (int h = 0; h < 4; ++h) {
                ac[h * 2 + 0] += bflo(pw[h]);
                ac[h * 2 + 1] += bfhi(pw[h]);
            }
        }
    }
    for (; j < c; ++j) {
        uint4 v0 = T[(size_t)sr[s + j] * 8 + l];
        const uint_t* pw = reinterpret_cast<const uint_t*>(&v0);
        #pragma unroll
        for (int h = 0; h < 4; ++h) {
            ac[h * 2 + 0] += bflo(pw[h]);
            ac[h * 2 + 1] += bfhi(pw[h]);
        }
    }
    float inv = 1.0f / fmaxf((float)c, 1.0f);
    float4* po = reinterpret_cast<float4*>(out + (size_t)node * 64) + l * 2;
    float4 p0 = po[0], p1 = po[1];
    p0.x += ac[0] * inv; p0.y += ac[1] * inv; p0.z += ac[2] * inv; p0.w += ac[3] * inv;
    p1.x += ac[4] * inv; p1.y += ac[5] * inv; p1.z += ac[6] * inv; p1.w += ac[7] * inv;
    po[0] = p0; po[1] = p1;
}

// ---------------- A-tile stage: 32 rows x 256 K bf16 = 16 KB, XOR-swizzled ----------------
#define STAGE_A32(Ag, mt, b)                                                        \
    {                                                                               \
        int base_ = (mt) * 32;                                                      \
        _Pragma("unroll")                                                           \
        for (int ii = 0; ii < 2; ++ii) {                                            \
            int s_ = ii * 512 + tid;                                                \
            int row_ = s_ >> 5, ks_ = s_ & 31;                                      \
            int ksl_ = ks_ ^ (row_ & 7);                                            \
            int gr_ = base_ + row_; if (gr_ >= Nn) gr_ = Nn - 1;                    \
            GLOAD((Ag) + (size_t)gr_ * 256 + ksl_ * 8, &sA[b][(s_ - lane) * 8]);    \
        }                                                                           \
    }

// ================= fused layer-1 + layer-2 GEMM, BM=32, 2 blocks/CU =================
// 8 waves, 1M x 8N. Per wave: L1 32 rows x 32 cols (wf1), L2 32 rows x 16 cols (wf2).
// job0: A=cu --wc10--> h_u (LDS) --wc20--> tu | op(+b_p2)
// job1: A=cp --wc11--> h_p --wc21--> tp | ou(+b_u2)
__global__ __launch_bounds__(512, 4) void k_mmf(
    const us_t* __restrict__ cu, const us_t* __restrict__ cp,
    const us_t* __restrict__ wc10, const us_t* __restrict__ wc11,
    const us_t* __restrict__ wc20, const us_t* __restrict__ wc21,
    const float* __restrict__ bu1, const float* __restrict__ bp1,
    const float* __restrict__ bu2, const float* __restrict__ bp2,
    us_t* __restrict__ tu, us_t* __restrict__ tp,
    float* __restrict__ ou, float* __restrict__ op) {
    __shared__ us_t sA[2][32 * 256];
    __shared__ us_t sH[32 * SHP];
    int tid = threadIdx.x, lane = tid & 63;
    int wc = tid >> 6;            // wave id 0..7 = N-slot
    int job = blockIdx.y;
    const us_t* Ag = job ? cp : cu;
    const us_t* W1 = job ? wc11 : wc10;
    const us_t* W2 = job ? wc21 : wc20;
    const float* b1 = job ? bp1 : bu1;
    const float* b2 = job ? bu2 : bp2;
    us_t* T = job ? tp : tu;
    float* O = job ? ou : op;

    // W1 frags: 32 out-cols per wave, K=256
    short8 wf1[2][8];
    #pragma unroll
    for (int n = 0; n < 2; ++n)
        #pragma unroll
        for (int ks = 0; ks < 8; ++ks) {
            int col = wc * 32 + n * 16 + (lane & 15);
            wf1[n][ks] = *reinterpret_cast<const short8*>(
                W1 + (size_t)col * 256 + ks * 32 + (lane >> 4) * 8);
        }
    float bv1[2];
    #pragma unroll
    for (int n = 0; n < 2; ++n) bv1[n] = b1[wc * 32 + n * 16 + (lane & 15)];

    // W2 frags: 16 out-cols per wave, K=256
    short8 wf2[8];
    #pragma unroll
    for (int ks = 0; ks < 8; ++ks) {
        int col = wc * 16 + (lane & 15);
        wf2[ks] = *reinterpret_cast<const short8*>(
            W2 + (size_t)col * 256 + ks * 32 + (lane >> 4) * 8);
    }
    int col2 = wc * 16 + (lane & 15);
    float bv2 = (col2 >= 64) ? b2[col2 - 64] : 0.f;
    bool top2 = col2 < 64;
    int cc2 = top2 ? col2 : col2 - 64;

    int bx = blockIdx.x;
    int NT = (MT32 - 1 - bx) / GXF + 1;
    STAGE_A32(Ag, bx, 0);
    for (int t = 0; t < NT; ++t) {
        int mt = bx + t * GXF;
        if (t + 1 < NT) {
            STAGE_A32(Ag, bx + (t + 1) * GXF, (t + 1) & 1);
            asm volatile("s_waitcnt vmcnt(2)" ::: "memory");
        } else {
            asm volatile("s_waitcnt vmcnt(0)" ::: "memory");
        }
        __syncthreads();   // sA[cur] ready; prior-tile sH readers done
        const us_t* sAc = sA[t & 1];

        // ---- layer-1 MFMAs: 32x32 per wave ----
        f32x4 acc1[2][2];
        #pragma unroll
        for (int m = 0; m < 2; ++m)
            #pragma unroll
            for (int n = 0; n < 2; ++n)
                #pragma unroll
                for (int i = 0; i < 4; ++i) acc1[m][n][i] = 0.f;

        #pragma unroll
        for (int ks = 0; ks < 8; ++ks) {
            short8 af[2];
            #pragma unroll
            for (int m = 0; m < 2; ++m) {
                int row = m * 16 + (lane & 15);
                int sl = (ks * 4 + (lane >> 4)) ^ (row & 7);
                af[m] = *reinterpret_cast<const short8*>(&sAc[row * 256 + sl * 8]);
            }
            #pragma unroll
            for (int m = 0; m < 2; ++m)
                #pragma unroll
                for (int n = 0; n < 2; ++n)
                    acc1[m][n] = __builtin_amdgcn_mfma_f32_16x16x32_bf16(
                        af[m], wf1[n][ks], acc1[m][n], 0, 0, 0);
        }

        // ---- h tile -> LDS (bf16, relu+bias) ----
        #pragma unroll
        for (int n = 0; n < 2; ++n) {
            int col = wc * 32 + n * 16 + (lane & 15);
            #pragma unroll
            for (int m = 0; m < 2; ++m) {
                int r0 = m * 16 + ((lane >> 4) << 2);
                #pragma unroll
                for (int j = 0; j < 4; ++j)
                    sH[(r0 + j) * SHP + col] =
                        f2bf(fmaxf(acc1[m][n][j] + bv1[n], 0.f));
            }
        }
        __syncthreads();   // sH complete

        // ---- layer-2 MFMAs: 32x16 per wave ----
        f32x4 acc2[2];
        #pragma unroll
        for (int m = 0; m < 2; ++m)
            #pragma unroll
            for (int i = 0; i < 4; ++i) acc2[m][i] = 0.f;

        #pragma unroll
        for (int ks = 0; ks < 8; ++ks) {
            short8 af2[2];
            #pragma unroll
            for (int m = 0; m < 2; ++m) {
                int row = m * 16 + (lane & 15);
                af2[m] = *reinterpret_cast<const short8*>(
                    &sH[row * SHP + ks * 32 + (lane >> 4) * 8]);
            }
            #pragma unroll
            for (int m = 0; m < 2; ++m)
                acc2[m] = __builtin_amdgcn_mfma_f32_16x16x32_bf16(
                    af2[m], wf2[ks], acc2[m], 0, 0, 0);
        }

        int mbase = mt * 32;
        #pragma unroll
        for (int m = 0; m < 2; ++m) {
            int row0 = mbase + m * 16 + ((lane >> 4) << 2);
            #pragma unroll
            for (int j = 0; j < 4; ++j) {
                int row = row0 + j;
                if (row >= Nn) continue;
                float v = acc2[m][j] + bv2;
                if (top2) T[(size_t)row * 64 + cc2] = f2bf(v);
                else      O[(size_t)row * 64 + cc2] = v;
            }
        }
        // next iteration's top barrier separates these sH reads from the next writes
    }
}

// ---------------- launch ----------------
extern "C" void kernel_launch(void* const* d_in, const int* in_sizes, int n_in,
                              void* d_out, int out_size, void* d_ws, size_t ws_size,
                              hipStream_t stream) {
    const float* x_user    = (const float*)d_in[0];
    const float* x_product = (const float*)d_in[1];
    const int*   ei        = (const int*)d_in[2];
    const float* w_u1_l = (const float*)d_in[3];
    const float* b_u1   = (const float*)d_in[4];
    const float* w_u1_r = (const float*)d_in[5];
    const float* w_p1_l = (const float*)d_in[6];
    const float* b_p1   = (const float*)d_in[7];
    const float* w_p1_r = (const float*)d_in[8];
    const float* w_u2_l = (const float*)d_in[9];
    const float* b_u2   = (const float*)d_in[10];
    const float* w_u2_r = (const float*)d_in[11];
    const float* w_p2_l = (const float*)d_in[12];
    const float* b_p2   = (const float*)d_in[13];
    const float* w_p2_r = (const float*)d_in[14];

    float* out_u = (float*)d_out;
    float* out_p = out_u + (size_t)Nn * CLSS;

    char* w = (char*)d_ws;
    int* bin_cnt  = (int*)w; w += (size_t)2 * NBIN * 4;
    int* off  = (int*)w;  w += (size_t)2 * Nn * 4;
    int* cnt  = (int*)w;  w += (size_t)2 * Nn * 4;
    int* src_p = (int*)w; w += (size_t)Ee * 4;
    int* src_u = (int*)w; w += (size_t)Ee * 4;
    uint_t* ent_p = (uint_t*)w; w += (size_t)NBIN * BCAP * 4;
    uint_t* ent_u = (uint_t*)w; w += (size_t)NBIN * BCAP * 4;
    uintptr_t a = (uintptr_t)w; a = (a + 255) & ~(uintptr_t)255; w = (char*)a;
    us_t* cu   = (us_t*)w; w += (size_t)Nn * 256 * 2;   // [mean_u | x_prod]
    us_t* cp   = (us_t*)w; w += (size_t)Nn * 256 * 2;   // [mean_p | x_user]
    uint_t* xf8u = (uint_t*)w; w += (size_t)Nn * FIN;
    uint_t* xf8p = (uint_t*)w; w += (size_t)Nn * FIN;
    us_t* tbuf_u = (us_t*)w; w += (size_t)Nn * CLSS * 2;
    us_t* tbuf_p = (us_t*)w; w += (size_t)Nn * CLSS * 2;
    us_t* wc10 = (us_t*)w; w += (size_t)256 * 256 * 2;
    us_t* wc11 = (us_t*)w; w += (size_t)256 * 256 * 2;
    us_t* wc20 = (us_t*)w; w += (size_t)128 * 256 * 2;
    us_t* wc21 = (us_t*)w; w += (size_t)128 * 256 * 2;

    // ---- front-end: zero bin counters, then bin || cvtw || cvtx in one launch ----
    hipMemsetAsync(bin_cnt, 0, (size_t)2 * NBIN * 4, stream);
    k_front<<<NEB + 96 + 512, 512, 0, stream>>>(
        ei, x_user, x_product,
        w_u1_l, w_u1_r, w_p1_l, w_p1_r, w_u2_l, w_u2_r, w_p2_l, w_p2_r,
        cu, cp, xf8u, xf8p, wc10, wc11, wc20, wc21,
        bin_cnt, ent_p, ent_u);
    dim3 gsc(NBIN, 2);
    k_scatter<<<gsc, 512, 0, stream>>>(ent_p, ent_u, bin_cnt,
                                       off, cnt, src_p, src_u);

    // ---- layer 1 aggregation ----
    dim3 ga1((Nn + 31) / 32, 2);
    k_agg1<<<ga1, 256, 0, stream>>>((const uint4*)xf8u, (const uint4*)xf8p,
                                    off, cnt, src_p, src_u, cu, cp);

    // ---- fused layer-1 + layer-2 GEMM ----
    dim3 g1(GXF, 2);
    k_mmf<<<g1, 512, 0, stream>>>(cu, cp, wc10, wc11, wc20, wc21,
                                  b_u1, b_p1, b_u2, b_p2,
                                  tbuf_u, tbuf_p, out_u, out_p);

    // ---- layer 2 aggregation ----
    dim3 ga2((Nn + 31) / 32, 2);
    k_agg2<<<ga2, 256, 0, stream>>>((const uint4*)tbuf_u, (const uint4*)tbuf_p,
                                    off, cnt, src_p, src_u, out_u, out_p);
}

// Round 14
// 172.887 us; speedup vs baseline: 1.2920x; 1.0188x over previous
//
#include <hip/hip_runtime.h>
#include <stdint.h>

#define Nn 50000
#define Ee 800000
#define FIN 128
#define HIDD 256
#define CLSS 64

#define NBIN 98          // ceil(50000 / 512)
#define BSH 9
#define BINSZ 512
#define BCAP 16384
#define EPB 2048
#define NEB ((Ee + EPB - 1) / EPB)   // 391

#define MT32 1563        // ceil(50000/32)
#define GXF 256          // M-group blocks per job for fused GEMM (512 blocks total)

#define SHP 264          // padded sH row stride (us_t)

typedef unsigned int uint_t;
typedef unsigned short us_t;
typedef __attribute__((ext_vector_type(8))) short short8;
typedef __attribute__((ext_vector_type(4))) float f32x4;
typedef __attribute__((ext_vector_type(2))) float f32x2;

__device__ inline float bflo(uint_t v) { union { uint_t u; float f; } c; c.u = v << 16; return c.f; }
__device__ inline float bfhi(uint_t v) { union { uint_t u; float f; } c; c.u = v & 0xffff0000u; return c.f; }
__device__ inline us_t f2bf(float f) {
    union { float f; uint_t u; } c; c.f = f;
    uint_t u = c.u;
    u += 0x7fffu + ((u >> 16) & 1u);
    return (us_t)(u >> 16);
}

#define GLOAD(gp, lp)                                                      \
    __builtin_amdgcn_global_load_lds(                                      \
        (const __attribute__((address_space(1))) unsigned int*)(gp),       \
        (__attribute__((address_space(3))) unsigned int*)(lp), 16, 0, 0)

// ================= merged front-end: k_bin || cvtw || cvtx =================
__global__ __launch_bounds__(512) void k_front(
    const int* __restrict__ ei,
    const float* __restrict__ xu, const float* __restrict__ xp,
    const float* __restrict__ w1, const float* __restrict__ w2,
    const float* __restrict__ w3, const float* __restrict__ w4,
    const float* __restrict__ w5, const float* __restrict__ w6,
    const float* __restrict__ w7, const float* __restrict__ w8,
    us_t* __restrict__ cu, us_t* __restrict__ cp,
    uint_t* __restrict__ f8u, uint_t* __restrict__ f8p,
    us_t* __restrict__ wc10, us_t* __restrict__ wc11,
    us_t* __restrict__ wc20, us_t* __restrict__ wc21,
    int* __restrict__ bin_cnt,
    uint_t* __restrict__ ent_p, uint_t* __restrict__ ent_u) {
    __shared__ int hist[2 * NBIN];
    __shared__ int base[2 * NBIN];
    int bx = blockIdx.x, tid = threadIdx.x;

    if (bx < NEB) {
        int e0 = bx * EPB;
        int n = Ee - e0; if (n > EPB) n = EPB;
        for (int i = tid; i < 2 * NBIN; i += 512) hist[i] = 0;
        __syncthreads();
        for (int i = tid; i < n; i += 512) {
            int u = ei[e0 + i], p = ei[Ee + e0 + i];
            atomicAdd(&hist[p >> BSH], 1);
            atomicAdd(&hist[NBIN + (u >> BSH)], 1);
        }
        __syncthreads();
        for (int i = tid; i < 2 * NBIN; i += 512) {
            int c = hist[i];
            base[i] = c ? atomicAdd(&bin_cnt[i], c) : 0;
        }
        __syncthreads();
        for (int i = tid; i < 2 * NBIN; i += 512) hist[i] = base[i];
        __syncthreads();
        for (int i = tid; i < n; i += 512) {
            int u = ei[e0 + i], p = ei[Ee + e0 + i];
            int bp = p >> BSH, bu = u >> BSH;
            int rp = atomicAdd(&hist[bp], 1);
            if (rp < BCAP)
                ent_p[(size_t)bp * BCAP + rp] = ((uint_t)(p & (BINSZ - 1)) << 16) | (uint_t)u;
            int ru = atomicAdd(&hist[NBIN + bu], 1);
            if (ru < BCAP)
                ent_u[(size_t)bu * BCAP + ru] = ((uint_t)(u & (BINSZ - 1)) << 16) | (uint_t)p;
        }
    } else if (bx < NEB + 96) {
        int i = (bx - NEB) * 512 + tid;
        const float* wp; us_t* dst;
        if (i < 32768) {
            int seg = i >> 13; int loc = i & 8191;
            int row = loc >> 5, col = (loc & 31) * 4;
            switch (seg) {
                case 0: wp = w1; dst = wc10 + (size_t)row * 256 + col; break;
                case 1: wp = w2; dst = wc10 + (size_t)row * 256 + 128 + col; break;
                case 2: wp = w3; dst = wc11 + (size_t)row * 256 + col; break;
                default: wp = w4; dst = wc11 + (size_t)row * 256 + 128 + col; break;
            }
            float4 v = reinterpret_cast<const float4*>(wp)[i & 8191];
            ushort4 o;
            o.x = f2bf(v.x); o.y = f2bf(v.y); o.z = f2bf(v.z); o.w = f2bf(v.w);
            *reinterpret_cast<ushort4*>(dst) = o;
        } else {
            int j = i - 32768;
            int seg = j >> 12; int loc = j & 4095;
            switch (seg) {
                case 0: wp = w5; dst = wc20; break;
                case 1: wp = w6; dst = wc21 + 64 * 256; break;
                case 2: wp = w7; dst = wc21; break;
                default: wp = w8; dst = wc20 + 64 * 256; break;
            }
            float4 v = reinterpret_cast<const float4*>(wp)[loc];
            ushort4 o;
            o.x = f2bf(v.x); o.y = f2bf(v.y); o.z = f2bf(v.z); o.w = f2bf(v.w);
            reinterpret_cast<ushort4*>(dst)[loc] = o;
        }
    } else {
        int bcx = bx - NEB - 96;
        int side = bcx & 1;
        const float* in = side ? xp : xu;
        us_t* comb = side ? cu : cp;
        uint_t* o8 = side ? f8p : f8u;
        const int n4 = (Nn * FIN) / 4;
        int i = (bcx >> 1) * 512 + tid;
        int stride = 256 * 512;
        for (; i < n4; i += stride) {
            float4 v = reinterpret_cast<const float4*>(in)[i];
            ushort4 o;
            o.x = f2bf(v.x); o.y = f2bf(v.y); o.z = f2bf(v.z); o.w = f2bf(v.w);
            int node = i >> 5;
            int col = (i & 31) * 4;
            *reinterpret_cast<ushort4*>(comb + (size_t)node * 256 + 128 + col) = o;
            int pk = __builtin_amdgcn_cvt_pk_fp8_f32(v.x, v.y, 0, false);
            pk = __builtin_amdgcn_cvt_pk_fp8_f32(v.z, v.w, pk, true);
            o8[i] = (uint_t)pk;
        }
    }
}

// ---------------- per-bin scatter with inline bin-base scan ----------------
__global__ __launch_bounds__(512) void k_scatter(
    const uint_t* __restrict__ ent_p, const uint_t* __restrict__ ent_u,
    const int* __restrict__ bin_cnt,
    int* __restrict__ off, int* __restrict__ cnt,
    int* __restrict__ src_p, int* __restrict__ src_u) {
    __shared__ int ca[BINSZ];
    __shared__ int cb[BINSZ];
    __shared__ int bb[128];
    int side = blockIdx.y, b = blockIdx.x, t = threadIdx.x;
    const uint_t* E = (side ? ent_u : ent_p) + (size_t)b * BCAP;
    int* src = side ? src_u : src_p;

    if (t < 128) {
        int v = 0;
        if (t < NBIN) { v = bin_cnt[side * NBIN + t]; if (v > BCAP) v = BCAP; }
        bb[t] = v;
    }
    __syncthreads();
    #pragma unroll
    for (int d = 1; d < 128; d <<= 1) {
        int x = 0;
        if (t < 128 && t >= d) x = bb[t - d];
        __syncthreads();
        if (t < 128) bb[t] += x;
        __syncthreads();
    }
    int nb = bin_cnt[side * NBIN + b]; if (nb > BCAP) nb = BCAP;
    int base = bb[b] - nb;

    ca[t] = 0;
    __syncthreads();
    for (int i = t; i < nb; i += 512)
        atomicAdd(&ca[E[i] >> 16], 1);
    __syncthreads();
    int v = ca[t];
    int* A = ca; int* B = cb;
    #pragma unroll
    for (int d = 1; d < BINSZ; d <<= 1) {
        int x = A[t] + ((t >= d) ? A[t - d] : 0);
        B[t] = x;
        __syncthreads();
        int* tmp = A; A = B; B = tmp;
    }
    int excl = A[t] - v;
    B[t] = excl;
    __syncthreads();
    for (int i = t; i < nb; i += 512) {
        uint_t e = E[i];
        int sl = atomicAdd(&B[e >> 16], 1);
        src[base + sl] = (int)(e & 0xffffu);
    }
    int d = (b << BSH) + t;
    if (d < Nn) {
        off[side * Nn + d] = base + excl;
        cnt[side * Nn + d] = v;
    }
}

// ---------------- layer-1 mean aggregation: 8 lanes x uint4 per fp8 row ----------------
__global__ __launch_bounds__(256) void k_agg1(
    const uint4* __restrict__ xu8, const uint4* __restrict__ xp8,
    const int* __restrict__ off, const int* __restrict__ cnt,
    const int* __restrict__ src_p, const int* __restrict__ src_u,
    us_t* __restrict__ cu, us_t* __restrict__ cp) {
    int side = blockIdx.y;
    const uint4* X = side ? xp8 : xu8;
    const int* of = off + side * Nn;
    const int* cn = cnt + side * Nn;
    const int* sr = side ? src_u : src_p;
    us_t* out = side ? cp : cu;

    int node = blockIdx.x * 32 + (threadIdx.x >> 3);
    if (node >= Nn) return;
    int l = threadIdx.x & 7;
    int s = of[node], c = cn[node];
    float ac[16];
    #pragma unroll
    for (int i = 0; i < 16; ++i) ac[i] = 0.f;

    int j = 0;
    for (; j + 8 <= c; j += 8) {
        int ss[8];
        #pragma unroll
        for (int q = 0; q < 8; ++q) ss[q] = sr[s + j + q];
        uint4 vv[8];
        #pragma unroll
        for (int q = 0; q < 8; ++q) vv[q] = X[(size_t)ss[q] * 8 + l];
        #pragma unroll
        for (int q = 0; q < 8; ++q) {
            const uint_t* pw = reinterpret_cast<const uint_t*>(&vv[q]);
            #pragma unroll
            for (int h = 0; h < 4; ++h) {
                f32x2 plo = __builtin_amdgcn_cvt_pk_f32_fp8((int)pw[h], false);
                f32x2 phi = __builtin_amdgcn_cvt_pk_f32_fp8((int)pw[h], true);
                ac[h * 4 + 0] += plo[0]; ac[h * 4 + 1] += plo[1];
                ac[h * 4 + 2] += phi[0]; ac[h * 4 + 3] += phi[1];
            }
        }
    }
    for (; j < c; ++j) {
        uint4 v0 = X[(size_t)sr[s + j] * 8 + l];
        const uint_t* pw = reinterpret_cast<const uint_t*>(&v0);
        #pragma unroll
        for (int h = 0; h < 4; ++h) {
            f32x2 plo = __builtin_amdgcn_cvt_pk_f32_fp8((int)pw[h], false);
            f32x2 phi = __builtin_amdgcn_cvt_pk_f32_fp8((int)pw[h], true);
            ac[h * 4 + 0] += plo[0]; ac[h * 4 + 1] += plo[1];
            ac[h * 4 + 2] += phi[0]; ac[h * 4 + 3] += phi[1];
        }
    }
    float inv = 1.0f / fmaxf((float)c, 1.0f);
    uint_t ow[8];
    #pragma unroll
    for (int i = 0; i < 8; ++i)
        ow[i] = (uint_t)f2bf(ac[2 * i] * inv) | ((uint_t)f2bf(ac[2 * i + 1] * inv) << 16);
    uint4* dst = reinterpret_cast<uint4*>(out + (size_t)node * 256 + l * 16);
    uint4 o0 = {ow[0], ow[1], ow[2], ow[3]};
    uint4 o1 = {ow[4], ow[5], ow[6], ow[7]};
    dst[0] = o0;
    dst[1] = o1;
}

// ---------------- layer-2 mean aggregation: 8 lanes x uint4 per bf16 row ----------------
__global__ __launch_bounds__(256) void k_agg2(
    const uint4* __restrict__ tu, const uint4* __restrict__ tp,
    const int* __restrict__ off, const int* __restrict__ cnt,
    const int* __restrict__ src_p, const int* __restrict__ src_u,
    float* __restrict__ ou, float* __restrict__ op) {
    int side = blockIdx.y;
    const uint4* T = side ? tp : tu;
    const int* of = off + side * Nn;
    const int* cn = cnt + side * Nn;
    const int* sr = side ? src_u : src_p;
    float* out = side ? op : ou;

    int node = blockIdx.x * 32 + (threadIdx.x >> 3);
    if (node >= Nn) return;
    int l = threadIdx.x & 7;
    int s = of[node], c = cn[node];
    float ac[8];
    #pragma unroll
    for (int i = 0; i < 8; ++i) ac[i] = 0.f;

    int j = 0;
    for (; j + 8 <= c; j += 8) {
        int ss[8];
        #pragma unroll
        for (int q = 0; q < 8; ++q) ss[q] = sr[s + j + q];
        uint4 vv[8];
        #pragma unroll
        for (int q = 0; q < 8; ++q) vv[q] = T[(size_t)ss[q] * 8 + l];
        #pragma unroll
        for (int q = 0; q < 8; ++q) {
            const uint_t* pw = reinterpret_cast<const uint_t*>(&vv[q]);
            #pragma unroll
            for (int h = 0; h < 4; ++h) {
                ac[h * 2 + 0] += bflo(pw[h]);
                ac[h * 2 + 1] += bfhi(pw[h]);
            }
        }
    }
    for (; j < c; ++j) {
        uint4 v0 = T[(size_t)sr[s + j] * 8 + l];
        const uint_t* pw = reinterpret_cast<const uint_t*>(&v0);
        #pragma unroll
        for (int h = 0; h < 4; ++h) {
            ac[h * 2 + 0] += bflo(pw[h]);
            ac[h * 2 + 1] += bfhi(pw[h]);
        }
    }
    float inv = 1.0f / fmaxf((float)c, 1.0f);
    float4* po = reinterpret_cast<float4*>(out + (size_t)node * 64) + l * 2;
    float4 p0 = po[0], p1 = po[1];
    p0.x += ac[0] * inv; p0.y += ac[1] * inv; p0.z += ac[2] * inv; p0.w += ac[3] * inv;
    p1.x += ac[4] * inv; p1.y += ac[5] * inv; p1.z += ac[6] * inv; p1.w += ac[7] * inv;
    po[0] = p0; po[1] = p1;
}

// ---------------- A-tile stage: 32 rows x 256 K bf16 = 16 KB, XOR-swizzled ----------------
#define STAGE_A32(Ag, mt, b)                                                        \
    {                                                                               \
        int base_ = (mt) * 32;                                                      \
        _Pragma("unroll")                                                           \
        for (int ii = 0; ii < 2; ++ii) {                                            \
            int s_ = ii * 512 + tid;                                                \
            int row_ = s_ >> 5, ks_ = s_ & 31;                                      \
            int ksl_ = ks_ ^ (row_ & 7);                                            \
            int gr_ = base_ + row_; if (gr_ >= Nn) gr_ = Nn - 1;                    \
            GLOAD((Ag) + (size_t)gr_ * 256 + ksl_ * 8, &sA[b][(s_ - lane) * 8]);    \
        }                                                                           \
    }

// ================= fused layer-1 + layer-2 GEMM, BM=32, depth-2 pipeline =================
// 8 waves, 1M x 8N. 3 sA buffers; steady-state keeps 2 stages (4 loads/thread) in flight.
// job0: A=cu --wc10--> h_u (LDS) --wc20--> tu | op(+b_p2)
// job1: A=cp --wc11--> h_p --wc21--> tp | ou(+b_u2)
__global__ __launch_bounds__(512, 4) void k_mmf(
    const us_t* __restrict__ cu, const us_t* __restrict__ cp,
    const us_t* __restrict__ wc10, const us_t* __restrict__ wc11,
    const us_t* __restrict__ wc20, const us_t* __restrict__ wc21,
    const float* __restrict__ bu1, const float* __restrict__ bp1,
    const float* __restrict__ bu2, const float* __restrict__ bp2,
    us_t* __restrict__ tu, us_t* __restrict__ tp,
    float* __restrict__ ou, float* __restrict__ op) {
    __shared__ us_t sA[3][32 * 256];
    __shared__ us_t sH[32 * SHP];
    int tid = threadIdx.x, lane = tid & 63;
    int wc = tid >> 6;            // wave id 0..7 = N-slot
    int job = blockIdx.y;
    const us_t* Ag = job ? cp : cu;
    const us_t* W1 = job ? wc11 : wc10;
    const us_t* W2 = job ? wc21 : wc20;
    const float* b1 = job ? bp1 : bu1;
    const float* b2 = job ? bu2 : bp2;
    us_t* T = job ? tp : tu;
    float* O = job ? ou : op;

    // W1 frags: 32 out-cols per wave, K=256
    short8 wf1[2][8];
    #pragma unroll
    for (int n = 0; n < 2; ++n)
        #pragma unroll
        for (int ks = 0; ks < 8; ++ks) {
            int col = wc * 32 + n * 16 + (lane & 15);
            wf1[n][ks] = *reinterpret_cast<const short8*>(
                W1 + (size_t)col * 256 + ks * 32 + (lane >> 4) * 8);
        }
    float bv1[2];
    #pragma unroll
    for (int n = 0; n < 2; ++n) bv1[n] = b1[wc * 32 + n * 16 + (lane & 15)];

    // W2 frags: 16 out-cols per wave, K=256
    short8 wf2[8];
    #pragma unroll
    for (int ks = 0; ks < 8; ++ks) {
        int col = wc * 16 + (lane & 15);
        wf2[ks] = *reinterpret_cast<const short8*>(
            W2 + (size_t)col * 256 + ks * 32 + (lane >> 4) * 8);
    }
    int col2 = wc * 16 + (lane & 15);
    float bv2 = (col2 >= 64) ? b2[col2 - 64] : 0.f;
    bool top2 = col2 < 64;
    int cc2 = top2 ? col2 : col2 - 64;

    int bx = blockIdx.x;
    int NT = (MT32 - 1 - bx) / GXF + 1;
    // prologue: stages 0 and 1 in flight
    STAGE_A32(Ag, bx, 0);
    if (NT > 1) STAGE_A32(Ag, bx + GXF, 1);
    for (int t = 0; t < NT; ++t) {
        int mt = bx + t * GXF;
        if (t + 2 < NT) {
            STAGE_A32(Ag, bx + (t + 2) * GXF, (t + 2) % 3);
            asm volatile("s_waitcnt vmcnt(4)" ::: "memory");   // stage t complete
        } else if (t + 1 < NT) {
            asm volatile("s_waitcnt vmcnt(2)" ::: "memory");   // stage t complete
        } else {
            asm volatile("s_waitcnt vmcnt(0)" ::: "memory");
        }
        __syncthreads();   // sA[t%3] ready; prior-tile sH readers done
        const us_t* sAc = sA[t % 3];

        // ---- layer-1 MFMAs: 32x32 per wave ----
        f32x4 acc1[2][2];
        #pragma unroll
        for (int m = 0; m < 2; ++m)
            #pragma unroll
            for (int n = 0; n < 2; ++n)
                #pragma unroll
                for (int i = 0; i < 4; ++i) acc1[m][n][i] = 0.f;

        #pragma unroll
        for (int ks = 0; ks < 8; ++ks) {
            short8 af[2];
            #pragma unroll
            for (int m = 0; m < 2; ++m) {
                int row = m * 16 + (lane & 15);
                int sl = (ks * 4 + (lane >> 4)) ^ (row & 7);
                af[m] = *reinterpret_cast<const short8*>(&sAc[row * 256 + sl * 8]);
            }
            #pragma unroll
            for (int m = 0; m < 2; ++m)
                #pragma unroll
                for (int n = 0; n < 2; ++n)
                    acc1[m][n] = __builtin_amdgcn_mfma_f32_16x16x32_bf16(
                        af[m], wf1[n][ks], acc1[m][n], 0, 0, 0);
        }

        // ---- h tile -> LDS (bf16, relu+bias) ----
        #pragma unroll
        for (int n = 0; n < 2; ++n) {
            int col = wc * 32 + n * 16 + (lane & 15);
            #pragma unroll
            for (int m = 0; m < 2; ++m) {
                int r0 = m * 16 + ((lane >> 4) << 2);
                #pragma unroll
                for (int j = 0; j < 4; ++j)
                    sH[(r0 + j) * SHP + col] =
                        f2bf(fmaxf(acc1[m][n][j] + bv1[n], 0.f));
            }
        }
        __syncthreads();   // sH complete

        // ---- layer-2 MFMAs: 32x16 per wave ----
        f32x4 acc2[2];
        #pragma unroll
        for (int m = 0; m < 2; ++m)
            #pragma unroll
            for (int i = 0; i < 4; ++i) acc2[m][i] = 0.f;

        #pragma unroll
        for (int ks = 0; ks < 8; ++ks) {
            short8 af2[2];
            #pragma unroll
            for (int m = 0; m < 2; ++m) {
                int row = m * 16 + (lane & 15);
                af2[m] = *reinterpret_cast<const short8*>(
                    &sH[row * SHP + ks * 32 + (lane >> 4) * 8]);
            }
            #pragma unroll
            for (int m = 0; m < 2; ++m)
                acc2[m] = __builtin_amdgcn_mfma_f32_16x16x32_bf16(
                    af2[m], wf2[ks], acc2[m], 0, 0, 0);
        }

        int mbase = mt * 32;
        #pragma unroll
        for (int m = 0; m < 2; ++m) {
            int row0 = mbase + m * 16 + ((lane >> 4) << 2);
            #pragma unroll
            for (int j = 0; j < 4; ++j) {
                int row = row0 + j;
                if (row >= Nn) continue;
                float v = acc2[m][j] + bv2;
                if (top2) T[(size_t)row * 64 + cc2] = f2bf(v);
                else      O[(size_t)row * 64 + cc2] = v;
            }
        }
        // next iteration's top barrier separates these sH reads from the next writes
    }
}

// ---------------- launch ----------------
extern "C" void kernel_launch(void* const* d_in, const int* in_sizes, int n_in,
                              void* d_out, int out_size, void* d_ws, size_t ws_size,
                              hipStream_t stream) {
    const float* x_user    = (const float*)d_in[0];
    const float* x_product = (const float*)d_in[1];
    const int*   ei        = (const int*)d_in[2];
    const float* w_u1_l = (const float*)d_in[3];
    const float* b_u1   = (const float*)d_in[4];
    const float* w_u1_r = (const float*)d_in[5];
    const float* w_p1_l = (const float*)d_in[6];
    const float* b_p1   = (const float*)d_in[7];
    const float* w_p1_r = (const float*)d_in[8];
    const float* w_u2_l = (const float*)d_in[9];
    const float* b_u2   = (const float*)d_in[10];
    const float* w_u2_r = (const float*)d_in[11];
    const float* w_p2_l = (const float*)d_in[12];
    const float* b_p2   = (const float*)d_in[13];
    const float* w_p2_r = (const float*)d_in[14];

    float* out_u = (float*)d_out;
    float* out_p = out_u + (size_t)Nn * CLSS;

    char* w = (char*)d_ws;
    int* bin_cnt  = (int*)w; w += (size_t)2 * NBIN * 4;
    int* off  = (int*)w;  w += (size_t)2 * Nn * 4;
    int* cnt  = (int*)w;  w += (size_t)2 * Nn * 4;
    int* src_p = (int*)w; w += (size_t)Ee * 4;
    int* src_u = (int*)w; w += (size_t)Ee * 4;
    uint_t* ent_p = (uint_t*)w; w += (size_t)NBIN * BCAP * 4;
    uint_t* ent_u = (uint_t*)w; w += (size_t)NBIN * BCAP * 4;
    uintptr_t a = (uintptr_t)w; a = (a + 255) & ~(uintptr_t)255; w = (char*)a;
    us_t* cu   = (us_t*)w; w += (size_t)Nn * 256 * 2;   // [mean_u | x_prod]
    us_t* cp   = (us_t*)w; w += (size_t)Nn * 256 * 2;   // [mean_p | x_user]
    uint_t* xf8u = (uint_t*)w; w += (size_t)Nn * FIN;
    uint_t* xf8p = (uint_t*)w; w += (size_t)Nn * FIN;
    us_t* tbuf_u = (us_t*)w; w += (size_t)Nn * CLSS * 2;
    us_t* tbuf_p = (us_t*)w; w += (size_t)Nn * CLSS * 2;
    us_t* wc10 = (us_t*)w; w += (size_t)256 * 256 * 2;
    us_t* wc11 = (us_t*)w; w += (size_t)256 * 256 * 2;
    us_t* wc20 = (us_t*)w; w += (size_t)128 * 256 * 2;
    us_t* wc21 = (us_t*)w; w += (size_t)128 * 256 * 2;

    // ---- front-end: zero bin counters, then bin || cvtw || cvtx in one launch ----
    hipMemsetAsync(bin_cnt, 0, (size_t)2 * NBIN * 4, stream);
    k_front<<<NEB + 96 + 512, 512, 0, stream>>>(
        ei, x_user, x_product,
        w_u1_l, w_u1_r, w_p1_l, w_p1_r, w_u2_l, w_u2_r, w_p2_l, w_p2_r,
        cu, cp, xf8u, xf8p, wc10, wc11, wc20, wc21,
        bin_cnt, ent_p, ent_u);
    dim3 gsc(NBIN, 2);
    k_scatter<<<gsc, 512, 0, stream>>>(ent_p, ent_u, bin_cnt,
                                       off, cnt, src_p, src_u);

    // ---- layer 1 aggregation ----
    dim3 ga1((Nn + 31) / 32, 2);
    k_agg1<<<ga1, 256, 0, stream>>>((const uint4*)xf8u, (const uint4*)xf8p,
                                    off, cnt, src_p, src_u, cu, cp);

    // ---- fused layer-1 + layer-2 GEMM ----
    dim3 g1(GXF, 2);
    k_mmf<<<g1, 512, 0, stream>>>(cu, cp, wc10, wc11, wc20, wc21,
                                  b_u1, b_p1, b_u2, b_p2,
                                  tbuf_u, tbuf_p, out_u, out_p);

    // ---- layer 2 aggregation ----
    dim3 ga2((Nn + 31) / 32, 2);
    k_agg2<<<ga2, 256, 0, stream>>>((const uint4*)tbuf_u, (const uint4*)tbuf_p,
                                    off, cnt, src_p, src_u, out_u, out_p);
}